// Round 10
// baseline (547.111 us; speedup 1.0000x reference)
//
#include <hip/hip_runtime.h>

typedef __bf16 bf16_t;
typedef __bf16 bf16x8 __attribute__((ext_vector_type(8)));
typedef __bf16 bf16x4 __attribute__((ext_vector_type(4)));
typedef float f32x16 __attribute__((ext_vector_type(16)));

#define MB 512
#define GROWS 128     // pair rows per g-block (4 mtiles of 32)
#define GT_PER_B 5    // ceil(625/128)

// ================= conv1: CIN=3, 75x75 -> 38x38 ============
// Round-10: staging rewritten as a ROW LOOP — thread owns fixed (ci,c) computed once
// (old: 2 magic-mul div/mods per element = ~20 VALU instr/elem; new: ~7). 384 thr, 6 waves.
// Stats in f64 atomics (fp32 atomic-order jitter caused the round-1 divergence).
__global__ __launch_bounds__(384, 6) void conv1_bn(const float* __restrict__ img,
                                                   const float* __restrict__ wT,
                                                   const float* __restrict__ bias,
                                                   float* __restrict__ out,
                                                   double* __restrict__ statsOut)
{
    __shared__ float in_s[3 * 21 * 77];   // 19,404 B
    __shared__ float red[48];
    int bid = blockIdx.x;
    int n = bid >> 2, tile = bid & 3;
    int oh0 = tile * 10;
    int tid = threadIdx.x;

    // staging: 231 threads own one (ci,c) column each; 21 row iterations
    {
        int sci = tid / 77, sc = tid - sci * 77;
        bool act = tid < 3 * 77;
        int iwS = sc - 1;
        bool wok = (unsigned)iwS < 75u;
        const float* ibase = img + (size_t)((n * 3 + (act ? sci : 0)) * 75) * 75 + iwS;
        float* obase = in_s + sci * (21 * 77) + sc;
#pragma unroll 1
        for (int r = 0; r < 21; ++r) {
            int ih = 2 * oh0 - 1 + r;
            if (act) {
                float v = 0.f;
                if (wok && (unsigned)ih < 75u) v = ibase[(size_t)ih * 75];
                obase[r * 77] = v;
            }
        }
    }
    __syncthreads();

    int cg = tid >> 6, lane = tid & 63, co0 = cg * 4;   // 6 waves x 4 co
    int nvr = 38 - oh0; if (nvr > 10) nvr = 10;
    int nposv = nvr * 38;
    int off[6];
    bool pv[6];
#pragma unroll
    for (int j = 0; j < 6; ++j) {
        int p = lane + j * 64;
        pv[j] = p < nposv;
        int pc = pv[j] ? p : 0;
        int r0 = pc / 38, c0 = pc - r0 * 38;
        off[j] = (r0 * 2) * 77 + c0 * 2;
    }
    float acc[4][6];
#pragma unroll
    for (int c = 0; c < 4; ++c)
#pragma unroll
        for (int j = 0; j < 6; ++j) acc[c][j] = 0.f;

#pragma unroll 1
    for (int ci = 0; ci < 3; ++ci) {
        const float* ip = in_s + ci * (21 * 77);
        const float* wp = wT + ci * 9 * 24 + co0;
#pragma unroll
        for (int kh = 0; kh < 3; ++kh) {
#pragma unroll
            for (int kw = 0; kw < 3; ++kw) {
                float iv[6];
#pragma unroll
                for (int j = 0; j < 6; ++j) iv[j] = ip[off[j] + kh * 77 + kw];
                const float* wr = wp + (kh * 3 + kw) * 24;
                float2 w01 = *(const float2*)(wr);
                float2 w23 = *(const float2*)(wr + 2);
#pragma unroll
                for (int j = 0; j < 6; ++j) {
                    acc[0][j] = fmaf(iv[j], w01.x, acc[0][j]);
                    acc[1][j] = fmaf(iv[j], w01.y, acc[1][j]);
                    acc[2][j] = fmaf(iv[j], w23.x, acc[2][j]);
                    acc[3][j] = fmaf(iv[j], w23.y, acc[3][j]);
                }
            }
        }
    }

    float sst[4], sq[4];
#pragma unroll
    for (int c = 0; c < 4; ++c) { sst[c] = 0.f; sq[c] = 0.f; }
#pragma unroll
    for (int c = 0; c < 4; ++c) {
        float bv = bias[co0 + c];
#pragma unroll
        for (int j = 0; j < 6; ++j) {
            if (pv[j]) {
                int p = lane + j * 64;
                int r = p / 38, q = p - r * 38;
                float v = fmaxf(acc[c][j] + bv, 0.f);
                out[((n * 24 + co0 + c) * 38 + oh0 + r) * 38 + q] = v;
                sst[c] += v; sq[c] += v * v;
            }
        }
    }
#pragma unroll
    for (int o = 1; o < 64; o <<= 1) {
#pragma unroll
        for (int c = 0; c < 4; ++c) {
            sst[c] += __shfl_xor(sst[c], o);
            sq[c]  += __shfl_xor(sq[c], o);
        }
    }
    if (lane == 0) {
#pragma unroll
        for (int c = 0; c < 4; ++c) {
            red[(co0 + c) * 2]     = sst[c];
            red[(co0 + c) * 2 + 1] = sq[c];
        }
    }
    __syncthreads();
    if (tid < 48) atomicAdd(&statsOut[tid], (double)red[tid]);
}

// ============ conv2/3/4: CIN=24, staged in 24/CIB phases; COB co per block; NT threads ==
// Round-10: staging rewritten as a ROW LOOP (fixed (ci,c) per thread, computed once;
// per row: pointer-stride load + fma + ds_write). CIB*ICW <= NT for every instantiation
// (312/252/132). Values written identical; ci summation order unchanged; stats f64-atomic.
template <int HIN, int WIN, int HOUT, int WOUT, int OHT, int NP, int CIB, int COB, int NT>
__global__ __launch_bounds__(NT, 6) void conv24_bn(const float* __restrict__ in,
                                                   const float* __restrict__ wT,
                                                   const float* __restrict__ bias,
                                                   const double* __restrict__ statsIn,
                                                   const float* __restrict__ gIn,
                                                   const float* __restrict__ bIn, float invcntIn,
                                                   float* __restrict__ out,
                                                   double* __restrict__ statsOut, int tilesPerImg)
{
    constexpr int IR = 2 * OHT + 1;
    constexpr int ICW = 2 * WOUT + 1;
    constexpr int NPH = 24 / CIB;
    constexpr int NCO = 24 / COB;      // co-groups per image-tile
    constexpr int NW  = NT / 64;       // waves per block
    constexpr int CPW = COB / NW;      // co per wave (6/4/3/2)
    static_assert(CIB * ICW <= NT, "staging row-loop needs CIB*ICW <= NT");
    __shared__ float in_s[CIB * IR * ICW];
    __shared__ float aff[48];
    __shared__ float red[48];

    int bid = blockIdx.x;
    int n = bid / (tilesPerImg * NCO);
    int rem = bid - n * (tilesPerImg * NCO);
    int tile = rem / NCO;
    int coBase = (rem - tile * NCO) * COB;
    int oh0 = tile * OHT;
    int tid = threadIdx.x;

    if (tid < 24) {
        double meand = statsIn[tid * 2] * (double)invcntIn;
        double vard  = statsIn[tid * 2 + 1] * (double)invcntIn - meand * meand;
        float mean = (float)meand;
        float s    = gIn[tid] * rsqrtf((float)vard + 1e-5f);
        aff[tid * 2] = s;
        aff[tid * 2 + 1] = bIn[tid] - mean * s;
    }
    __syncthreads();

    // staging geometry (phase-invariant, computed once)
    int sci = tid / ICW, sc = tid - sci * ICW;
    bool act = tid < CIB * ICW;
    int iwS = sc - 1;
    bool wok = (unsigned)iwS < (unsigned)WIN;
    float* obase = in_s + sci * (IR * ICW) + sc;

    int cg = tid >> 6, lane = tid & 63, co0 = coBase + cg * CPW;
    int nvr = HOUT - oh0; if (nvr > OHT) nvr = OHT;
    int nposv = nvr * WOUT;
    int off[NP];
    bool pv[NP];
#pragma unroll
    for (int j = 0; j < NP; ++j) {
        int p = lane + j * 64;
        pv[j] = p < nposv;
        int pc = pv[j] ? p : 0;
        int r0 = pc / WOUT, c0 = pc - r0 * WOUT;
        off[j] = (r0 * 2) * ICW + c0 * 2;
    }
    float acc[CPW][NP];
#pragma unroll
    for (int c = 0; c < CPW; ++c)
#pragma unroll
        for (int j = 0; j < NP; ++j) acc[c][j] = 0.f;

#pragma unroll 1
    for (int ph = 0; ph < NPH; ++ph) {
        if (ph) __syncthreads();   // all waves done reading previous phase's LDS
        {
            int gci = ph * CIB + sci;
            float sA = 0.f, sB = 0.f;
            if (act) { sA = aff[gci * 2]; sB = aff[gci * 2 + 1]; }
            const float* ibase = in + (size_t)((n * 24 + (act ? gci : 0)) * HIN) * WIN + iwS;
#pragma unroll 1
            for (int r = 0; r < IR; ++r) {
                int ih = 2 * oh0 - 1 + r;
                if (act) {
                    float v = 0.f;
                    if (wok && (unsigned)ih < (unsigned)HIN) v = sA * ibase[(size_t)ih * WIN] + sB;
                    obase[r * ICW] = v;
                }
            }
        }
        __syncthreads();

#pragma unroll 1
        for (int ci = 0; ci < CIB; ++ci) {
            const float* ip = in_s + ci * (IR * ICW);
            const float* wp = wT + (ph * CIB + ci) * 9 * 24 + co0;
#pragma unroll
            for (int kh = 0; kh < 3; ++kh) {
#pragma unroll
                for (int kw = 0; kw < 3; ++kw) {
                    float iv[NP];
#pragma unroll
                    for (int j = 0; j < NP; ++j) iv[j] = ip[off[j] + kh * ICW + kw];
                    const float* wr = wp + (kh * 3 + kw) * 24;
                    if constexpr (CPW == 6) {
                        float2 w01 = *(const float2*)(wr);
                        float2 w23 = *(const float2*)(wr + 2);
                        float2 w45 = *(const float2*)(wr + 4);
#pragma unroll
                        for (int j = 0; j < NP; ++j) {
                            acc[0][j] = fmaf(iv[j], w01.x, acc[0][j]);
                            acc[1][j] = fmaf(iv[j], w01.y, acc[1][j]);
                            acc[2][j] = fmaf(iv[j], w23.x, acc[2][j]);
                            acc[3][j] = fmaf(iv[j], w23.y, acc[3][j]);
                            acc[4][j] = fmaf(iv[j], w45.x, acc[4][j]);
                            acc[5][j] = fmaf(iv[j], w45.y, acc[5][j]);
                        }
                    } else if constexpr (CPW == 4) {
                        float2 w01 = *(const float2*)(wr);
                        float2 w23 = *(const float2*)(wr + 2);
#pragma unroll
                        for (int j = 0; j < NP; ++j) {
                            acc[0][j] = fmaf(iv[j], w01.x, acc[0][j]);
                            acc[1][j] = fmaf(iv[j], w01.y, acc[1][j]);
                            acc[2][j] = fmaf(iv[j], w23.x, acc[2][j]);
                            acc[3][j] = fmaf(iv[j], w23.y, acc[3][j]);
                        }
                    } else if constexpr (CPW == 3) {
                        float w0 = wr[0], w1 = wr[1], w2 = wr[2];
#pragma unroll
                        for (int j = 0; j < NP; ++j) {
                            acc[0][j] = fmaf(iv[j], w0, acc[0][j]);
                            acc[1][j] = fmaf(iv[j], w1, acc[1][j]);
                            acc[2][j] = fmaf(iv[j], w2, acc[2][j]);
                        }
                    } else {   // CPW == 2
                        float2 w01 = *(const float2*)(wr);
#pragma unroll
                        for (int j = 0; j < NP; ++j) {
                            acc[0][j] = fmaf(iv[j], w01.x, acc[0][j]);
                            acc[1][j] = fmaf(iv[j], w01.y, acc[1][j]);
                        }
                    }
                }
            }
        }
    }

    float sst[CPW], sq[CPW];
#pragma unroll
    for (int c = 0; c < CPW; ++c) { sst[c] = 0.f; sq[c] = 0.f; }
#pragma unroll
    for (int c = 0; c < CPW; ++c) {
        float bv = bias[co0 + c];
#pragma unroll
        for (int j = 0; j < NP; ++j) {
            if (pv[j]) {
                int p = lane + j * 64;
                int r = p / WOUT, q = p - r * WOUT;
                float v = fmaxf(acc[c][j] + bv, 0.f);
                out[((n * 24 + co0 + c) * HOUT + oh0 + r) * WOUT + q] = v;
                sst[c] += v; sq[c] += v * v;
            }
        }
    }
#pragma unroll
    for (int o = 1; o < 64; o <<= 1) {
#pragma unroll
        for (int c = 0; c < CPW; ++c) {
            sst[c] += __shfl_xor(sst[c], o);
            sq[c]  += __shfl_xor(sq[c], o);
        }
    }
    if (lane == 0) {
#pragma unroll
        for (int c = 0; c < CPW; ++c) {
            int lc = cg * CPW + c;   // local channel within this block's COB
            red[lc * 2]     = sst[c];
            red[lc * 2 + 1] = sq[c];
        }
    }
    __syncthreads();
    if (tid < COB * 2) atomicAdd(&statsOut[coBase * 2 + tid], (double)red[tid]);
}

// ---------------- build bf16 features: xf26 = [BN4(conv4) 24ch, coords 2] ; qst bf16 ----------------
__global__ void build_features(const float* __restrict__ y4, const double* __restrict__ stats4,
                               const float* __restrict__ g4, const float* __restrict__ b4,
                               const float* __restrict__ qst,
                               bf16_t* __restrict__ xf26, bf16_t* __restrict__ qstb)
{
    int idx = blockIdx.x * 256 + threadIdx.x;
    if (idx < MB * 11) qstb[idx] = (bf16_t)qst[idx];
    if (idx >= MB * 25) return;
    int b = idx / 25, p = idx % 25;
    const double invcnt = 1.0 / (MB * 25);
#pragma unroll
    for (int ch = 0; ch < 24; ++ch) {
        double meand = stats4[ch * 2] * invcnt;
        double vard  = stats4[ch * 2 + 1] * invcnt - meand * meand;
        float mean = (float)meand;
        float s    = g4[ch] * rsqrtf((float)vard + 1e-5f);
        float v    = s * y4[(b * 24 + ch) * 25 + p] + (b4[ch] - mean * s);
        xf26[idx * 26 + ch] = (bf16_t)v;
    }
    xf26[idx * 26 + 24] = (bf16_t)((p / 5.0f - 2.0f) * 0.5f);
    xf26[idx * 26 + 25] = (bf16_t)(((float)(p % 5) - 2.0f) * 0.5f);
}

// ------- weight prep: g-weights in MFMA-A-frag order, fp32 transposes for f-MLP, conv wT --------
// Wf layout per layer: [nt (N/32)][ks (K/16)][lane 0..63][j 0..7]
//   element = W[nt*32 + (lane&31)][ks*16 + (lane>>5)*8 + j]
__device__ __forceinline__ void frag256(int idx, const float* __restrict__ gw, bf16_t* __restrict__ Wf)
{
    int j = idx & 7, lane = (idx >> 3) & 63, ks = (idx >> 9) & 15, nt = idx >> 13;
    int n = nt * 32 + (lane & 31), k = ks * 16 + (lane >> 5) * 8 + j;
    Wf[idx] = (bf16_t)gw[n * 256 + k];
}

// total work items: 16384 + 3*65536 + 2*65536 + 648 + 3*5184 = 360,264 -> grid 1408x256 = 360,448
__global__ void prep_weights(const float* __restrict__ gw1, const float* __restrict__ gw2,
                             const float* __restrict__ gw3, const float* __restrict__ gw4,
                             const float* __restrict__ fw1, const float* __restrict__ fw2,
                             const float* __restrict__ c1w, const float* __restrict__ c2w,
                             const float* __restrict__ c3w, const float* __restrict__ c4w,
                             bf16_t* __restrict__ W1f, bf16_t* __restrict__ W2f,
                             bf16_t* __restrict__ W3f, bf16_t* __restrict__ W4f,
                             float* __restrict__ fw1T, float* __restrict__ fw2T,
                             float* __restrict__ wT1, float* __restrict__ wT2,
                             float* __restrict__ wT3, float* __restrict__ wT4)
{
    int idx = blockIdx.x * 256 + threadIdx.x;
    if (idx < 16384) {  // W1: K=64 (63 + zero pad), [8 nt][4 ks][64][8]
        int j = idx & 7, lane = (idx >> 3) & 63, ks = (idx >> 9) & 3, nt = idx >> 11;
        int n = nt * 32 + (lane & 31), k = ks * 16 + (lane >> 5) * 8 + j;
        W1f[idx] = (k < 63) ? (bf16_t)gw1[n * 63 + k] : (bf16_t)0.0f;
        return;
    }
    idx -= 16384;
    if (idx < 65536) { frag256(idx, gw2, W2f); return; }
    idx -= 65536;
    if (idx < 65536) { frag256(idx, gw3, W3f); return; }
    idx -= 65536;
    if (idx < 65536) { frag256(idx, gw4, W4f); return; }
    idx -= 65536;
    if (idx < 65536) { int k = idx >> 8, nn = idx & 255; fw1T[idx] = fw1[nn * 256 + k]; return; }
    idx -= 65536;
    if (idx < 65536) { int k = idx >> 8, nn = idx & 255; fw2T[idx] = fw2[nn * 256 + k]; return; }
    idx -= 65536;
    if (idx < 648)   { int k = idx / 24, co = idx - k * 24; wT1[idx] = c1w[co * 27 + k]; return; }
    idx -= 648;
    if (idx < 5184)  { int k = idx / 24, co = idx - k * 24; wT2[idx] = c2w[co * 216 + k]; return; }
    idx -= 5184;
    if (idx < 5184)  { int k = idx / 24, co = idx - k * 24; wT3[idx] = c3w[co * 216 + k]; return; }
    idx -= 5184;
    if (idx < 5184)  { int k = idx / 24, co = idx - k * 24; wT4[idx] = c4w[co * 216 + k]; return; }
}

// ---------------- fused g-MLP: 32x32x16 MFMA, swapped operands (A=W, B=h^T), swizzled LDS ----------------
// Round-10: hf DOUBLE-BUFFER — load ks+1's 4 LDS fragments before ks's 8-MFMA cluster so
// the ~120cy ds_read latency hides under the 256-cycle MFMA cluster (per-CU serial-sum model:
// MFMA 55 + LDS 52 + VALU 43 ≈ 153us measured; within-wave ILP is the missing overlap at
// 2 waves/SIMD). All buffer selects compile-time (ks fully unrolled). Accumulation order
// unchanged -> bit-identical output. No intra-layer barriers = not the m133-null regime.

template <int NKS>  // K/16: 4 for layer1, 16 for layers 2-4
__device__ __forceinline__ void g_layer(const bf16_t* hs, const bf16_t* __restrict__ Wf,
                                        int wid, int lane, f32x16 (&acc)[4][2])
{
    int m31 = lane & 31, half = lane >> 5;
#pragma unroll
    for (int mt = 0; mt < 4; ++mt)
#pragma unroll
        for (int nt = 0; nt < 2; ++nt) acc[mt][nt] = (f32x16)(0.f);

    const bf16_t* wbase0 = Wf + (size_t)(((wid * 2 + 0) * NKS) * 64 + lane) * 8;
    const bf16_t* wbase1 = Wf + (size_t)(((wid * 2 + 1) * NKS) * 64 + lane) * 8;
    bf16x8 wA[2][4], wB[2][4];
#pragma unroll
    for (int k = 0; k < 4; ++k) {   // preload weight quarter 0
        wA[0][k] = *(const bf16x8*)(wbase0 + (size_t)k * 512);
        wA[1][k] = *(const bf16x8*)(wbase1 + (size_t)k * 512);
    }
    bf16x8 hfA[4], hfB[4];
#pragma unroll
    for (int mt = 0; mt < 4; ++mt)   // preload hf for ks=0
        hfA[mt] = *(const bf16x8*)(hs + (mt * 32 + m31) * 256 + (((0 * 2 + half) ^ m31) << 3));

#pragma unroll
    for (int ks = 0; ks < NKS; ++ks) {
        // prefetch next weight quarter at quarter start (4 ks of MFMA to hide L2 latency)
        if ((ks & 3) == 0 && ks + 4 < NKS) {
#pragma unroll
            for (int k = 0; k < 4; ++k) {
                if (((ks >> 2) & 1) == 0) {
                    wB[0][k] = *(const bf16x8*)(wbase0 + (size_t)(ks + 4 + k) * 512);
                    wB[1][k] = *(const bf16x8*)(wbase1 + (size_t)(ks + 4 + k) * 512);
                } else {
                    wA[0][k] = *(const bf16x8*)(wbase0 + (size_t)(ks + 4 + k) * 512);
                    wA[1][k] = *(const bf16x8*)(wbase1 + (size_t)(ks + 4 + k) * 512);
                }
            }
        }
        // prefetch next ks's hf fragments (hide ds_read latency under this ks's MFMAs)
        if (ks + 1 < NKS) {
            int kc1 = (ks + 1) * 2 + half;
#pragma unroll
            for (int mt = 0; mt < 4; ++mt) {
                bf16x8 v = *(const bf16x8*)(hs + (mt * 32 + m31) * 256 + ((kc1 ^ m31) << 3));
                if ((ks & 1) == 0) hfB[mt] = v; else hfA[mt] = v;
            }
        }
        // MFMA cluster for current ks
#pragma unroll
        for (int mt = 0; mt < 4; ++mt) {
            bf16x8 hcur = ((ks & 1) == 0) ? hfA[mt] : hfB[mt];
            bf16x8 w0 = (((ks >> 2) & 1) == 0) ? wA[0][ks & 3] : wB[0][ks & 3];
            bf16x8 w1 = (((ks >> 2) & 1) == 0) ? wA[1][ks & 3] : wB[1][ks & 3];
            acc[mt][0] = __builtin_amdgcn_mfma_f32_32x32x16_bf16(w0, hcur, acc[mt][0], 0, 0, 0);
            acc[mt][1] = __builtin_amdgcn_mfma_f32_32x32x16_bf16(w1, hcur, acc[mt][1], 0, 0, 0);
        }
    }
}

__device__ __forceinline__ void g_store(bf16_t* hs, const float* __restrict__ bias,
                                        int wid, int lane, f32x16 (&acc)[4][2])
{
    int m31 = lane & 31, half = lane >> 5;
#pragma unroll
    for (int mt = 0; mt < 4; ++mt) {
        int m = mt * 32 + m31;
#pragma unroll
        for (int nt = 0; nt < 2; ++nt) {
            int nbase = (wid * 2 + nt) * 32;
#pragma unroll
            for (int g = 0; g < 4; ++g) {
                int n0 = nbase + g * 8 + half * 4;
                float4 bv = *(const float4*)(bias + n0);
                bf16x4 v;
                v[0] = (bf16_t)fmaxf(acc[mt][nt][g * 4 + 0] + bv.x, 0.f);
                v[1] = (bf16_t)fmaxf(acc[mt][nt][g * 4 + 1] + bv.y, 0.f);
                v[2] = (bf16_t)fmaxf(acc[mt][nt][g * 4 + 2] + bv.z, 0.f);
                v[3] = (bf16_t)fmaxf(acc[mt][nt][g * 4 + 3] + bv.w, 0.f);
                int chunk = n0 >> 3;  // half*4 < 8, so chunk = (nbase + g*8) >> 3
                *(bf16x4*)(hs + m * 256 + ((chunk ^ m31) << 3) + (half << 2)) = v;
            }
        }
    }
}

__global__ void __launch_bounds__(256, 2)
g_mlp(const bf16_t* __restrict__ xf26, const bf16_t* __restrict__ qstb,
      const bf16_t* __restrict__ W1f, const bf16_t* __restrict__ W2f,
      const bf16_t* __restrict__ W3f, const bf16_t* __restrict__ W4f,
      const float* __restrict__ b1, const float* __restrict__ b2,
      const float* __restrict__ b3, const float* __restrict__ b4,
      float* __restrict__ xg5)
{
    __shared__ __align__(16) bf16_t hs[GROWS * 256];   // 65,536 B
    int b    = blockIdx.x / GT_PER_B;
    int tile = blockIdx.x % GT_PER_B;
    int tid  = threadIdx.x;

    // stage features (64 bf16 per row -> chunks 0..7, swizzled)
    for (int i = tid; i < GROWS * 8; i += 256) {
        int m = i >> 3, c = i & 7;
        int p = tile * GROWS + m;
        bf16x8 v;
        if (p < 625) {
            int a = p / 25, cp = p - a * 25;
            const bf16_t* f1 = xf26 + (b * 25 + cp) * 26;
            const bf16_t* f2 = xf26 + (b * 25 + a) * 26;
            const bf16_t* f3 = qstb + b * 11;
#pragma unroll
            for (int j = 0; j < 8; ++j) {
                int col = c * 8 + j;
                bf16_t u = (bf16_t)0.0f;
                if (col < 26) u = f1[col];
                else if (col < 52) u = f2[col - 26];
                else if (col < 63) u = f3[col - 52];
                v[j] = u;
            }
        } else {
#pragma unroll
            for (int j = 0; j < 8; ++j) v[j] = (bf16_t)0.0f;
        }
        *(bf16x8*)(hs + m * 256 + ((c ^ (m & 31)) << 3)) = v;
    }
    __syncthreads();

    int wid = tid >> 6, lane = tid & 63;
    int m31 = lane & 31, half = lane >> 5;
    f32x16 acc[4][2];

    g_layer<4>(hs, W1f, wid, lane, acc);
    __syncthreads(); g_store(hs, b1, wid, lane, acc); __syncthreads();
    g_layer<16>(hs, W2f, wid, lane, acc);
    __syncthreads(); g_store(hs, b2, wid, lane, acc); __syncthreads();
    g_layer<16>(hs, W3f, wid, lane, acc);
    __syncthreads(); g_store(hs, b3, wid, lane, acc); __syncthreads();
    g_layer<16>(hs, W4f, wid, lane, acc);

    // epilogue: relu(acc + b4), mask invalid rows, sum over m, plain store into xg5 slot
#pragma unroll
    for (int nt = 0; nt < 2; ++nt) {
        int nbase = (wid * 2 + nt) * 32;
        float bf[16];
#pragma unroll
        for (int r = 0; r < 16; ++r)
            bf[r] = b4[nbase + (r & 3) + 8 * (r >> 2) + 4 * half];
        f32x16 t = (f32x16)(0.f);
#pragma unroll
        for (int mt = 0; mt < 4; ++mt) {
            int p = tile * GROWS + mt * 32 + m31;
            if (p < 625) {
#pragma unroll
                for (int r = 0; r < 16; ++r)
                    t[r] += fmaxf(acc[mt][nt][r] + bf[r], 0.f);
            }
        }
#pragma unroll
        for (int off = 1; off < 32; off <<= 1) {
#pragma unroll
            for (int r = 0; r < 16; ++r) t[r] += __shfl_xor(t[r], off);
        }
        if (m31 == 0) {
#pragma unroll
            for (int r = 0; r < 16; ++r) {
                int nn = nbase + (r & 3) + 8 * (r >> 2) + 4 * half;
                xg5[(b * GT_PER_B + tile) * 256 + nn] = t[r];
            }
        }
    }
}

// ---------------- f-MLP (fp32) + log_softmax, one block per batch element ----------------
// Sums the 5 per-tile g_mlp slots (replaces global atomics).
__global__ void f_mlp(const float* __restrict__ xg5, const float* __restrict__ fw1T, const float* __restrict__ fb1,
                      const float* __restrict__ fw2T, const float* __restrict__ fb2,
                      const float* __restrict__ fw3, const float* __restrict__ fb3,
                      float* __restrict__ out)
{
    __shared__ float xa[256], xb[256], lg[10];
    int b = blockIdx.x, t = threadIdx.x;
    float s0 = 0.f;
#pragma unroll
    for (int i = 0; i < GT_PER_B; ++i) s0 += xg5[(b * GT_PER_B + i) * 256 + t];
    xa[t] = s0;
    __syncthreads();
    float a = fb1[t];
    for (int k = 0; k < 256; ++k) a += fw1T[k * 256 + t] * xa[k];
    xb[t] = fmaxf(a, 0.f);
    __syncthreads();
    a = fb2[t];
    for (int k = 0; k < 256; ++k) a += fw2T[k * 256 + t] * xb[k];
    xa[t] = fmaxf(a, 0.f);
    __syncthreads();
    if (t < 10) {
        float s = fb3[t];
        for (int k = 0; k < 256; ++k) s += fw3[t * 256 + k] * xa[k];
        lg[t] = s;
    }
    __syncthreads();
    if (t == 0) {
        float m = lg[0];
        for (int i = 1; i < 10; ++i) m = fmaxf(m, lg[i]);
        float s = 0.f;
        for (int i = 0; i < 10; ++i) s += expf(lg[i] - m);
        float ls = m + logf(s);
        for (int i = 0; i < 10; ++i) out[b * 10 + i] = lg[i] - ls;
    }
}

// ---------------- launch ----------------
extern "C" void kernel_launch(void* const* d_in, const int* in_sizes, int n_in,
                              void* d_out, int out_size, void* d_ws, size_t ws_size,
                              hipStream_t stream)
{
    (void)in_sizes; (void)n_in; (void)out_size; (void)ws_size;
    const float* img  = (const float*)d_in[0];
    const float* qst  = (const float*)d_in[1];
    const float* c1w  = (const float*)d_in[2];
    const float* c1b  = (const float*)d_in[3];
    const float* bn1g = (const float*)d_in[4];
    const float* bn1b = (const float*)d_in[5];
    const float* c2w  = (const float*)d_in[6];
    const float* c2b  = (const float*)d_in[7];
    const float* bn2g = (const float*)d_in[8];
    const float* bn2b = (const float*)d_in[9];
    const float* c3w  = (const float*)d_in[10];
    const float* c3b  = (const float*)d_in[11];
    const float* bn3g = (const float*)d_in[12];
    const float* bn3b = (const float*)d_in[13];
    const float* c4w  = (const float*)d_in[14];
    const float* c4b  = (const float*)d_in[15];
    const float* bn4g = (const float*)d_in[16];
    const float* bn4b = (const float*)d_in[17];
    const float* gw1  = (const float*)d_in[18];
    const float* gb1  = (const float*)d_in[19];
    const float* gw2  = (const float*)d_in[20];
    const float* gb2  = (const float*)d_in[21];
    const float* gw3  = (const float*)d_in[22];
    const float* gb3  = (const float*)d_in[23];
    const float* gw4  = (const float*)d_in[24];
    const float* gb4  = (const float*)d_in[25];
    const float* fw1  = (const float*)d_in[26];
    const float* fb1  = (const float*)d_in[27];
    const float* fw2  = (const float*)d_in[28];
    const float* fb2  = (const float*)d_in[29];
    const float* fw3  = (const float*)d_in[30];
    const float* fb3  = (const float*)d_in[31];

    const int Y1 = 512 * 24 * 38 * 38;
    const int Y2 = 512 * 24 * 19 * 19;
    const int Y3 = 512 * 24 * 10 * 10;
    const int Y4 = 512 * 24 * 5 * 5;

    // stats in DOUBLE at the head of ws (8B-aligned); everything else after
    double* stats = (double*)d_ws;       // [4 layers][24 ch][sum, sumsq] = 192 doubles
    float* fp = (float*)(stats + 192);
    float* y1    = fp;  fp += Y1;
    float* y2    = fp;  fp += Y2;
    float* y3    = fp;  fp += Y3;
    float* y4    = fp;  fp += Y4;
    float* xg5   = fp;  fp += 512 * GT_PER_B * 256;   // per-tile partial sums (no atomics)
    float* fw1T  = fp;  fp += 65536;
    float* fw2T  = fp;  fp += 65536;
    float* wT1   = fp;  fp += 648;       // conv weights transposed [k][24]
    float* wT2   = fp;  fp += 5184;
    float* wT3   = fp;  fp += 5184;
    float* wT4   = fp;  fp += 5184;
    bf16_t* bp   = (bf16_t*)fp;
    bf16_t* xf26 = bp;  bp += 512 * 25 * 26;
    bf16_t* qstb = bp;  bp += 512 * 11;
    bf16_t* W1f  = bp;  bp += 16384;     // g-weights in MFMA frag order
    bf16_t* W2f  = bp;  bp += 65536;
    bf16_t* W3f  = bp;  bp += 65536;
    bf16_t* W4f  = bp;  bp += 65536;

    hipMemsetAsync(stats, 0, 192 * sizeof(double), stream);

    // grid MUST cover all 360,264 work items (ceil -> 1408 blocks)
    prep_weights<<<1408, 256, 0, stream>>>(gw1, gw2, gw3, gw4, fw1, fw2, c1w, c2w, c3w, c4w,
                                           W1f, W2f, W3f, W4f, fw1T, fw2T,
                                           wT1, wT2, wT3, wT4);

    // conv1: 4 row-tiles of 10 per image, 384-thread blocks (6 waves x 4 co)
    conv1_bn<<<2048, 384, 0, stream>>>(img, wT1, c1b, y1, stats + 0);

    // conv2: 2 row-tiles of 10, 3 staging phases of 8 ch, 384thr (CPW=4) -> 24 waves/CU
    conv24_bn<38, 38, 19, 19, 10, 3, 8, 24, 384><<<1024, 384, 0, stream>>>(
        y1, wT2, c2b, stats + 0, bn1g, bn1b, 1.f / (512.f * 1444.f),
        y2, stats + 48, 2);

    // conv3: co-split (12 co per block), 384thr (CPW=2) -> 24 waves/CU
    conv24_bn<19, 19, 10, 10, 10, 2, 12, 12, 384><<<1024, 384, 0, stream>>>(
        y2, wT3, c3b, stats + 48, bn2g, bn2b, 1.f / (512.f * 361.f),
        y3, stats + 96, 1);

    // conv4: co-split (12 co per block), 384thr (CPW=2)
    conv24_bn<10, 10, 5, 5, 5, 1, 12, 12, 384><<<1024, 384, 0, stream>>>(
        y3, wT4, c4b, stats + 96, bn3g, bn3b, 1.f / (512.f * 100.f),
        y4, stats + 144, 1);

    build_features<<<50, 256, 0, stream>>>(y4, stats + 144, bn4g, bn4b, qst, xf26, qstb);

    g_mlp<<<512 * GT_PER_B, 256, 0, stream>>>(xf26, qstb, W1f, W2f, W3f, W4f,
                                              gb1, gb2, gb3, gb4, xg5);

    f_mlp<<<512, 256, 0, stream>>>(xg5, fw1T, fb1, fw2T, fb2, fw3, fb3, (float*)d_out);
}

// Round 11
// 546.241 us; speedup vs baseline: 1.0016x; 1.0016x over previous
//
#include <hip/hip_runtime.h>

typedef __bf16 bf16_t;
typedef __bf16 bf16x8 __attribute__((ext_vector_type(8)));
typedef __bf16 bf16x4 __attribute__((ext_vector_type(4)));
typedef float f32x16 __attribute__((ext_vector_type(16)));

#define MB 512
#define GROWS 128     // pair rows per g-block (4 mtiles of 32)
#define GT_PER_B 5    // ceil(625/128)

// ================= conv1: CIN=3, 75x75 -> 38x38 ============
// Round-11: staging row loop FULLY UNROLLED (r10's `unroll 1` serialized 21 dependent
// global-load->LDS-write iterations, exposing ~300cy latency per row; full unroll keeps
// the cheap per-row addressing AND issues all loads together). 384 thr, 6 waves.
// Stats in f64 atomics (fp32 atomic-order jitter caused the round-1 divergence).
__global__ __launch_bounds__(384, 6) void conv1_bn(const float* __restrict__ img,
                                                   const float* __restrict__ wT,
                                                   const float* __restrict__ bias,
                                                   float* __restrict__ out,
                                                   double* __restrict__ statsOut)
{
    __shared__ float in_s[3 * 21 * 77];   // 19,404 B
    __shared__ float red[48];
    int bid = blockIdx.x;
    int n = bid >> 2, tile = bid & 3;
    int oh0 = tile * 10;
    int tid = threadIdx.x;

    // staging: 231 threads own one (ci,c) column each; 21 rows fully unrolled
    {
        int sci = tid / 77, sc = tid - sci * 77;
        bool act = tid < 3 * 77;
        int iwS = sc - 1;
        bool wok = (unsigned)iwS < 75u;
        const float* ibase = img + (size_t)((n * 3 + (act ? sci : 0)) * 75) * 75 + iwS;
        float* obase = in_s + sci * (21 * 77) + sc;
#pragma unroll
        for (int r = 0; r < 21; ++r) {
            int ih = 2 * oh0 - 1 + r;
            if (act) {
                float v = 0.f;
                if (wok && (unsigned)ih < 75u) v = ibase[(size_t)ih * 75];
                obase[r * 77] = v;
            }
        }
    }
    __syncthreads();

    int cg = tid >> 6, lane = tid & 63, co0 = cg * 4;   // 6 waves x 4 co
    int nvr = 38 - oh0; if (nvr > 10) nvr = 10;
    int nposv = nvr * 38;
    int off[6];
    bool pv[6];
#pragma unroll
    for (int j = 0; j < 6; ++j) {
        int p = lane + j * 64;
        pv[j] = p < nposv;
        int pc = pv[j] ? p : 0;
        int r0 = pc / 38, c0 = pc - r0 * 38;
        off[j] = (r0 * 2) * 77 + c0 * 2;
    }
    float acc[4][6];
#pragma unroll
    for (int c = 0; c < 4; ++c)
#pragma unroll
        for (int j = 0; j < 6; ++j) acc[c][j] = 0.f;

#pragma unroll 1
    for (int ci = 0; ci < 3; ++ci) {
        const float* ip = in_s + ci * (21 * 77);
        const float* wp = wT + ci * 9 * 24 + co0;
#pragma unroll
        for (int kh = 0; kh < 3; ++kh) {
#pragma unroll
            for (int kw = 0; kw < 3; ++kw) {
                float iv[6];
#pragma unroll
                for (int j = 0; j < 6; ++j) iv[j] = ip[off[j] + kh * 77 + kw];
                const float* wr = wp + (kh * 3 + kw) * 24;
                float2 w01 = *(const float2*)(wr);
                float2 w23 = *(const float2*)(wr + 2);
#pragma unroll
                for (int j = 0; j < 6; ++j) {
                    acc[0][j] = fmaf(iv[j], w01.x, acc[0][j]);
                    acc[1][j] = fmaf(iv[j], w01.y, acc[1][j]);
                    acc[2][j] = fmaf(iv[j], w23.x, acc[2][j]);
                    acc[3][j] = fmaf(iv[j], w23.y, acc[3][j]);
                }
            }
        }
    }

    float sst[4], sq[4];
#pragma unroll
    for (int c = 0; c < 4; ++c) { sst[c] = 0.f; sq[c] = 0.f; }
#pragma unroll
    for (int c = 0; c < 4; ++c) {
        float bv = bias[co0 + c];
#pragma unroll
        for (int j = 0; j < 6; ++j) {
            if (pv[j]) {
                int p = lane + j * 64;
                int r = p / 38, q = p - r * 38;
                float v = fmaxf(acc[c][j] + bv, 0.f);
                out[((n * 24 + co0 + c) * 38 + oh0 + r) * 38 + q] = v;
                sst[c] += v; sq[c] += v * v;
            }
        }
    }
#pragma unroll
    for (int o = 1; o < 64; o <<= 1) {
#pragma unroll
        for (int c = 0; c < 4; ++c) {
            sst[c] += __shfl_xor(sst[c], o);
            sq[c]  += __shfl_xor(sq[c], o);
        }
    }
    if (lane == 0) {
#pragma unroll
        for (int c = 0; c < 4; ++c) {
            red[(co0 + c) * 2]     = sst[c];
            red[(co0 + c) * 2 + 1] = sq[c];
        }
    }
    __syncthreads();
    if (tid < 48) atomicAdd(&statsOut[tid], (double)red[tid]);
}

// ============ conv2/3/4: CIN=24, staged in 24/CIB phases; COB co per block; NT threads ==
// Round-11: staging row loop FULLY UNROLLED (fixed (ci,c) per thread; per row one
// independent predicated load + fma + ds_write, all rows issued together — r10's
// `unroll 1` serialized them and cost +13us). CIB*ICW <= NT for every instantiation.
// Values written identical; ci summation order unchanged; stats f64-atomic.
template <int HIN, int WIN, int HOUT, int WOUT, int OHT, int NP, int CIB, int COB, int NT>
__global__ __launch_bounds__(NT, 6) void conv24_bn(const float* __restrict__ in,
                                                   const float* __restrict__ wT,
                                                   const float* __restrict__ bias,
                                                   const double* __restrict__ statsIn,
                                                   const float* __restrict__ gIn,
                                                   const float* __restrict__ bIn, float invcntIn,
                                                   float* __restrict__ out,
                                                   double* __restrict__ statsOut, int tilesPerImg)
{
    constexpr int IR = 2 * OHT + 1;
    constexpr int ICW = 2 * WOUT + 1;
    constexpr int NPH = 24 / CIB;
    constexpr int NCO = 24 / COB;      // co-groups per image-tile
    constexpr int NW  = NT / 64;       // waves per block
    constexpr int CPW = COB / NW;      // co per wave (6/4/3/2)
    static_assert(CIB * ICW <= NT, "staging row-loop needs CIB*ICW <= NT");
    __shared__ float in_s[CIB * IR * ICW];
    __shared__ float aff[48];
    __shared__ float red[48];

    int bid = blockIdx.x;
    int n = bid / (tilesPerImg * NCO);
    int rem = bid - n * (tilesPerImg * NCO);
    int tile = rem / NCO;
    int coBase = (rem - tile * NCO) * COB;
    int oh0 = tile * OHT;
    int tid = threadIdx.x;

    if (tid < 24) {
        double meand = statsIn[tid * 2] * (double)invcntIn;
        double vard  = statsIn[tid * 2 + 1] * (double)invcntIn - meand * meand;
        float mean = (float)meand;
        float s    = gIn[tid] * rsqrtf((float)vard + 1e-5f);
        aff[tid * 2] = s;
        aff[tid * 2 + 1] = bIn[tid] - mean * s;
    }
    __syncthreads();

    // staging geometry (phase-invariant, computed once)
    int sci = tid / ICW, sc = tid - sci * ICW;
    bool act = tid < CIB * ICW;
    int iwS = sc - 1;
    bool wok = (unsigned)iwS < (unsigned)WIN;
    float* obase = in_s + sci * (IR * ICW) + sc;

    int cg = tid >> 6, lane = tid & 63, co0 = coBase + cg * CPW;
    int nvr = HOUT - oh0; if (nvr > OHT) nvr = OHT;
    int nposv = nvr * WOUT;
    int off[NP];
    bool pv[NP];
#pragma unroll
    for (int j = 0; j < NP; ++j) {
        int p = lane + j * 64;
        pv[j] = p < nposv;
        int pc = pv[j] ? p : 0;
        int r0 = pc / WOUT, c0 = pc - r0 * WOUT;
        off[j] = (r0 * 2) * ICW + c0 * 2;
    }
    float acc[CPW][NP];
#pragma unroll
    for (int c = 0; c < CPW; ++c)
#pragma unroll
        for (int j = 0; j < NP; ++j) acc[c][j] = 0.f;

#pragma unroll 1
    for (int ph = 0; ph < NPH; ++ph) {
        if (ph) __syncthreads();   // all waves done reading previous phase's LDS
        {
            int gci = ph * CIB + sci;
            float sA = 0.f, sB = 0.f;
            if (act) { sA = aff[gci * 2]; sB = aff[gci * 2 + 1]; }
            const float* ibase = in + (size_t)((n * 24 + (act ? gci : 0)) * HIN) * WIN + iwS;
#pragma unroll
            for (int r = 0; r < IR; ++r) {
                int ih = 2 * oh0 - 1 + r;
                if (act) {
                    float v = 0.f;
                    if (wok && (unsigned)ih < (unsigned)HIN) v = sA * ibase[(size_t)ih * WIN] + sB;
                    obase[r * ICW] = v;
                }
            }
        }
        __syncthreads();

#pragma unroll 1
        for (int ci = 0; ci < CIB; ++ci) {
            const float* ip = in_s + ci * (IR * ICW);
            const float* wp = wT + (ph * CIB + ci) * 9 * 24 + co0;
#pragma unroll
            for (int kh = 0; kh < 3; ++kh) {
#pragma unroll
                for (int kw = 0; kw < 3; ++kw) {
                    float iv[NP];
#pragma unroll
                    for (int j = 0; j < NP; ++j) iv[j] = ip[off[j] + kh * ICW + kw];
                    const float* wr = wp + (kh * 3 + kw) * 24;
                    if constexpr (CPW == 6) {
                        float2 w01 = *(const float2*)(wr);
                        float2 w23 = *(const float2*)(wr + 2);
                        float2 w45 = *(const float2*)(wr + 4);
#pragma unroll
                        for (int j = 0; j < NP; ++j) {
                            acc[0][j] = fmaf(iv[j], w01.x, acc[0][j]);
                            acc[1][j] = fmaf(iv[j], w01.y, acc[1][j]);
                            acc[2][j] = fmaf(iv[j], w23.x, acc[2][j]);
                            acc[3][j] = fmaf(iv[j], w23.y, acc[3][j]);
                            acc[4][j] = fmaf(iv[j], w45.x, acc[4][j]);
                            acc[5][j] = fmaf(iv[j], w45.y, acc[5][j]);
                        }
                    } else if constexpr (CPW == 4) {
                        float2 w01 = *(const float2*)(wr);
                        float2 w23 = *(const float2*)(wr + 2);
#pragma unroll
                        for (int j = 0; j < NP; ++j) {
                            acc[0][j] = fmaf(iv[j], w01.x, acc[0][j]);
                            acc[1][j] = fmaf(iv[j], w01.y, acc[1][j]);
                            acc[2][j] = fmaf(iv[j], w23.x, acc[2][j]);
                            acc[3][j] = fmaf(iv[j], w23.y, acc[3][j]);
                        }
                    } else if constexpr (CPW == 3) {
                        float w0 = wr[0], w1 = wr[1], w2 = wr[2];
#pragma unroll
                        for (int j = 0; j < NP; ++j) {
                            acc[0][j] = fmaf(iv[j], w0, acc[0][j]);
                            acc[1][j] = fmaf(iv[j], w1, acc[1][j]);
                            acc[2][j] = fmaf(iv[j], w2, acc[2][j]);
                        }
                    } else {   // CPW == 2
                        float2 w01 = *(const float2*)(wr);
#pragma unroll
                        for (int j = 0; j < NP; ++j) {
                            acc[0][j] = fmaf(iv[j], w01.x, acc[0][j]);
                            acc[1][j] = fmaf(iv[j], w01.y, acc[1][j]);
                        }
                    }
                }
            }
        }
    }

    float sst[CPW], sq[CPW];
#pragma unroll
    for (int c = 0; c < CPW; ++c) { sst[c] = 0.f; sq[c] = 0.f; }
#pragma unroll
    for (int c = 0; c < CPW; ++c) {
        float bv = bias[co0 + c];
#pragma unroll
        for (int j = 0; j < NP; ++j) {
            if (pv[j]) {
                int p = lane + j * 64;
                int r = p / WOUT, q = p - r * WOUT;
                float v = fmaxf(acc[c][j] + bv, 0.f);
                out[((n * 24 + co0 + c) * HOUT + oh0 + r) * WOUT + q] = v;
                sst[c] += v; sq[c] += v * v;
            }
        }
    }
#pragma unroll
    for (int o = 1; o < 64; o <<= 1) {
#pragma unroll
        for (int c = 0; c < CPW; ++c) {
            sst[c] += __shfl_xor(sst[c], o);
            sq[c]  += __shfl_xor(sq[c], o);
        }
    }
    if (lane == 0) {
#pragma unroll
        for (int c = 0; c < CPW; ++c) {
            int lc = cg * CPW + c;   // local channel within this block's COB
            red[lc * 2]     = sst[c];
            red[lc * 2 + 1] = sq[c];
        }
    }
    __syncthreads();
    if (tid < COB * 2) atomicAdd(&statsOut[coBase * 2 + tid], (double)red[tid]);
}

// ---------------- build bf16 features: xf26 = [BN4(conv4) 24ch, coords 2] ; qst bf16 ----------------
__global__ void build_features(const float* __restrict__ y4, const double* __restrict__ stats4,
                               const float* __restrict__ g4, const float* __restrict__ b4,
                               const float* __restrict__ qst,
                               bf16_t* __restrict__ xf26, bf16_t* __restrict__ qstb)
{
    int idx = blockIdx.x * 256 + threadIdx.x;
    if (idx < MB * 11) qstb[idx] = (bf16_t)qst[idx];
    if (idx >= MB * 25) return;
    int b = idx / 25, p = idx % 25;
    const double invcnt = 1.0 / (MB * 25);
#pragma unroll
    for (int ch = 0; ch < 24; ++ch) {
        double meand = stats4[ch * 2] * invcnt;
        double vard  = stats4[ch * 2 + 1] * invcnt - meand * meand;
        float mean = (float)meand;
        float s    = g4[ch] * rsqrtf((float)vard + 1e-5f);
        float v    = s * y4[(b * 24 + ch) * 25 + p] + (b4[ch] - mean * s);
        xf26[idx * 26 + ch] = (bf16_t)v;
    }
    xf26[idx * 26 + 24] = (bf16_t)((p / 5.0f - 2.0f) * 0.5f);
    xf26[idx * 26 + 25] = (bf16_t)(((float)(p % 5) - 2.0f) * 0.5f);
}

// ------- weight prep: g-weights in MFMA-A-frag order, fp32 transposes for f-MLP, conv wT --------
// Wf layout per layer: [nt (N/32)][ks (K/16)][lane 0..63][j 0..7]
//   element = W[nt*32 + (lane&31)][ks*16 + (lane>>5)*8 + j]
__device__ __forceinline__ void frag256(int idx, const float* __restrict__ gw, bf16_t* __restrict__ Wf)
{
    int j = idx & 7, lane = (idx >> 3) & 63, ks = (idx >> 9) & 15, nt = idx >> 13;
    int n = nt * 32 + (lane & 31), k = ks * 16 + (lane >> 5) * 8 + j;
    Wf[idx] = (bf16_t)gw[n * 256 + k];
}

// total work items: 16384 + 3*65536 + 2*65536 + 648 + 3*5184 = 360,264 -> grid 1408x256 = 360,448
__global__ void prep_weights(const float* __restrict__ gw1, const float* __restrict__ gw2,
                             const float* __restrict__ gw3, const float* __restrict__ gw4,
                             const float* __restrict__ fw1, const float* __restrict__ fw2,
                             const float* __restrict__ c1w, const float* __restrict__ c2w,
                             const float* __restrict__ c3w, const float* __restrict__ c4w,
                             bf16_t* __restrict__ W1f, bf16_t* __restrict__ W2f,
                             bf16_t* __restrict__ W3f, bf16_t* __restrict__ W4f,
                             float* __restrict__ fw1T, float* __restrict__ fw2T,
                             float* __restrict__ wT1, float* __restrict__ wT2,
                             float* __restrict__ wT3, float* __restrict__ wT4)
{
    int idx = blockIdx.x * 256 + threadIdx.x;
    if (idx < 16384) {  // W1: K=64 (63 + zero pad), [8 nt][4 ks][64][8]
        int j = idx & 7, lane = (idx >> 3) & 63, ks = (idx >> 9) & 3, nt = idx >> 11;
        int n = nt * 32 + (lane & 31), k = ks * 16 + (lane >> 5) * 8 + j;
        W1f[idx] = (k < 63) ? (bf16_t)gw1[n * 63 + k] : (bf16_t)0.0f;
        return;
    }
    idx -= 16384;
    if (idx < 65536) { frag256(idx, gw2, W2f); return; }
    idx -= 65536;
    if (idx < 65536) { frag256(idx, gw3, W3f); return; }
    idx -= 65536;
    if (idx < 65536) { frag256(idx, gw4, W4f); return; }
    idx -= 65536;
    if (idx < 65536) { int k = idx >> 8, nn = idx & 255; fw1T[idx] = fw1[nn * 256 + k]; return; }
    idx -= 65536;
    if (idx < 65536) { int k = idx >> 8, nn = idx & 255; fw2T[idx] = fw2[nn * 256 + k]; return; }
    idx -= 65536;
    if (idx < 648)   { int k = idx / 24, co = idx - k * 24; wT1[idx] = c1w[co * 27 + k]; return; }
    idx -= 648;
    if (idx < 5184)  { int k = idx / 24, co = idx - k * 24; wT2[idx] = c2w[co * 216 + k]; return; }
    idx -= 5184;
    if (idx < 5184)  { int k = idx / 24, co = idx - k * 24; wT3[idx] = c3w[co * 216 + k]; return; }
    idx -= 5184;
    if (idx < 5184)  { int k = idx / 24, co = idx - k * 24; wT4[idx] = c4w[co * 216 + k]; return; }
}

// ---------------- fused g-MLP: 32x32x16 MFMA, swapped operands (A=W, B=h^T), swizzled LDS ----------------
// Round-11: reverted to the round-9 body (r10's hf double-buffer was NULL within noise —
// 153.4 -> 153.4us; 7th null micro-variant). g_mlp is pinned at ~153us / MfmaUtil 40%;
// only a full 8-phase rewrite would move it — deferred.

template <int NKS>
__device__ __forceinline__ void g_quarter(const bf16_t* hs, const bf16_t* __restrict__ wbase0,
                                          const bf16_t* __restrict__ wbase1,
                                          int q, int m31, int half,
                                          bf16x8 (&CUR)[2][4], bf16x8 (&NXT)[2][4],
                                          f32x16 (&acc)[4][2])
{
    if (q + 1 < NKS / 4) {   // prefetch next quarter's wf while this quarter's MFMAs run
#pragma unroll
        for (int k = 0; k < 4; ++k) {
            NXT[0][k] = *(const bf16x8*)(wbase0 + (size_t)((q + 1) * 4 + k) * 512);
            NXT[1][k] = *(const bf16x8*)(wbase1 + (size_t)((q + 1) * 4 + k) * 512);
        }
    }
#pragma unroll
    for (int kk = 0; kk < 4; ++kk) {
        int ks = q * 4 + kk;
        int kc = ks * 2 + half;
        bf16x8 hf[4];
#pragma unroll
        for (int mt = 0; mt < 4; ++mt) {
            int m = mt * 32 + m31;
            hf[mt] = *(const bf16x8*)(hs + m * 256 + ((kc ^ m31) << 3));
        }
#pragma unroll
        for (int mt = 0; mt < 4; ++mt) {
            acc[mt][0] = __builtin_amdgcn_mfma_f32_32x32x16_bf16(CUR[0][kk], hf[mt], acc[mt][0], 0, 0, 0);
            acc[mt][1] = __builtin_amdgcn_mfma_f32_32x32x16_bf16(CUR[1][kk], hf[mt], acc[mt][1], 0, 0, 0);
        }
    }
}

template <int NKS>  // K/16: 4 for layer1, 16 for layers 2-4
__device__ __forceinline__ void g_layer(const bf16_t* hs, const bf16_t* __restrict__ Wf,
                                        int wid, int lane, f32x16 (&acc)[4][2])
{
    int m31 = lane & 31, half = lane >> 5;
#pragma unroll
    for (int mt = 0; mt < 4; ++mt)
#pragma unroll
        for (int nt = 0; nt < 2; ++nt) acc[mt][nt] = (f32x16)(0.f);

    const bf16_t* wbase0 = Wf + (size_t)(((wid * 2 + 0) * NKS) * 64 + lane) * 8;
    const bf16_t* wbase1 = Wf + (size_t)(((wid * 2 + 1) * NKS) * 64 + lane) * 8;
    bf16x8 wA[2][4], wB[2][4];
#pragma unroll
    for (int k = 0; k < 4; ++k) {   // preload quarter 0
        wA[0][k] = *(const bf16x8*)(wbase0 + (size_t)k * 512);
        wA[1][k] = *(const bf16x8*)(wbase1 + (size_t)k * 512);
    }
#pragma unroll
    for (int q = 0; q < NKS / 4; ++q) {
        if ((q & 1) == 0) g_quarter<NKS>(hs, wbase0, wbase1, q, m31, half, wA, wB, acc);
        else              g_quarter<NKS>(hs, wbase0, wbase1, q, m31, half, wB, wA, acc);
    }
}

__device__ __forceinline__ void g_store(bf16_t* hs, const float* __restrict__ bias,
                                        int wid, int lane, f32x16 (&acc)[4][2])
{
    int m31 = lane & 31, half = lane >> 5;
#pragma unroll
    for (int mt = 0; mt < 4; ++mt) {
        int m = mt * 32 + m31;
#pragma unroll
        for (int nt = 0; nt < 2; ++nt) {
            int nbase = (wid * 2 + nt) * 32;
#pragma unroll
            for (int g = 0; g < 4; ++g) {
                int n0 = nbase + g * 8 + half * 4;
                float4 bv = *(const float4*)(bias + n0);
                bf16x4 v;
                v[0] = (bf16_t)fmaxf(acc[mt][nt][g * 4 + 0] + bv.x, 0.f);
                v[1] = (bf16_t)fmaxf(acc[mt][nt][g * 4 + 1] + bv.y, 0.f);
                v[2] = (bf16_t)fmaxf(acc[mt][nt][g * 4 + 2] + bv.z, 0.f);
                v[3] = (bf16_t)fmaxf(acc[mt][nt][g * 4 + 3] + bv.w, 0.f);
                int chunk = n0 >> 3;  // half*4 < 8, so chunk = (nbase + g*8) >> 3
                *(bf16x4*)(hs + m * 256 + ((chunk ^ m31) << 3) + (half << 2)) = v;
            }
        }
    }
}

__global__ void __launch_bounds__(256, 2)
g_mlp(const bf16_t* __restrict__ xf26, const bf16_t* __restrict__ qstb,
      const bf16_t* __restrict__ W1f, const bf16_t* __restrict__ W2f,
      const bf16_t* __restrict__ W3f, const bf16_t* __restrict__ W4f,
      const float* __restrict__ b1, const float* __restrict__ b2,
      const float* __restrict__ b3, const float* __restrict__ b4,
      float* __restrict__ xg5)
{
    __shared__ __align__(16) bf16_t hs[GROWS * 256];   // 65,536 B
    int b    = blockIdx.x / GT_PER_B;
    int tile = blockIdx.x % GT_PER_B;
    int tid  = threadIdx.x;

    // stage features (64 bf16 per row -> chunks 0..7, swizzled)
    for (int i = tid; i < GROWS * 8; i += 256) {
        int m = i >> 3, c = i & 7;
        int p = tile * GROWS + m;
        bf16x8 v;
        if (p < 625) {
            int a = p / 25, cp = p - a * 25;
            const bf16_t* f1 = xf26 + (b * 25 + cp) * 26;
            const bf16_t* f2 = xf26 + (b * 25 + a) * 26;
            const bf16_t* f3 = qstb + b * 11;
#pragma unroll
            for (int j = 0; j < 8; ++j) {
                int col = c * 8 + j;
                bf16_t u = (bf16_t)0.0f;
                if (col < 26) u = f1[col];
                else if (col < 52) u = f2[col - 26];
                else if (col < 63) u = f3[col - 52];
                v[j] = u;
            }
        } else {
#pragma unroll
            for (int j = 0; j < 8; ++j) v[j] = (bf16_t)0.0f;
        }
        *(bf16x8*)(hs + m * 256 + ((c ^ (m & 31)) << 3)) = v;
    }
    __syncthreads();

    int wid = tid >> 6, lane = tid & 63;
    int m31 = lane & 31, half = lane >> 5;
    f32x16 acc[4][2];

    g_layer<4>(hs, W1f, wid, lane, acc);
    __syncthreads(); g_store(hs, b1, wid, lane, acc); __syncthreads();
    g_layer<16>(hs, W2f, wid, lane, acc);
    __syncthreads(); g_store(hs, b2, wid, lane, acc); __syncthreads();
    g_layer<16>(hs, W3f, wid, lane, acc);
    __syncthreads(); g_store(hs, b3, wid, lane, acc); __syncthreads();
    g_layer<16>(hs, W4f, wid, lane, acc);

    // epilogue: relu(acc + b4), mask invalid rows, sum over m, plain store into xg5 slot
#pragma unroll
    for (int nt = 0; nt < 2; ++nt) {
        int nbase = (wid * 2 + nt) * 32;
        float bf[16];
#pragma unroll
        for (int r = 0; r < 16; ++r)
            bf[r] = b4[nbase + (r & 3) + 8 * (r >> 2) + 4 * half];
        f32x16 t = (f32x16)(0.f);
#pragma unroll
        for (int mt = 0; mt < 4; ++mt) {
            int p = tile * GROWS + mt * 32 + m31;
            if (p < 625) {
#pragma unroll
                for (int r = 0; r < 16; ++r)
                    t[r] += fmaxf(acc[mt][nt][r] + bf[r], 0.f);
            }
        }
#pragma unroll
        for (int off = 1; off < 32; off <<= 1) {
#pragma unroll
            for (int r = 0; r < 16; ++r) t[r] += __shfl_xor(t[r], off);
        }
        if (m31 == 0) {
#pragma unroll
            for (int r = 0; r < 16; ++r) {
                int nn = nbase + (r & 3) + 8 * (r >> 2) + 4 * half;
                xg5[(b * GT_PER_B + tile) * 256 + nn] = t[r];
            }
        }
    }
}

// ---------------- f-MLP (fp32) + log_softmax, one block per batch element ----------------
// Sums the 5 per-tile g_mlp slots (replaces global atomics).
__global__ void f_mlp(const float* __restrict__ xg5, const float* __restrict__ fw1T, const float* __restrict__ fb1,
                      const float* __restrict__ fw2T, const float* __restrict__ fb2,
                      const float* __restrict__ fw3, const float* __restrict__ fb3,
                      float* __restrict__ out)
{
    __shared__ float xa[256], xb[256], lg[10];
    int b = blockIdx.x, t = threadIdx.x;
    float s0 = 0.f;
#pragma unroll
    for (int i = 0; i < GT_PER_B; ++i) s0 += xg5[(b * GT_PER_B + i) * 256 + t];
    xa[t] = s0;
    __syncthreads();
    float a = fb1[t];
    for (int k = 0; k < 256; ++k) a += fw1T[k * 256 + t] * xa[k];
    xb[t] = fmaxf(a, 0.f);
    __syncthreads();
    a = fb2[t];
    for (int k = 0; k < 256; ++k) a += fw2T[k * 256 + t] * xb[k];
    xa[t] = fmaxf(a, 0.f);
    __syncthreads();
    if (t < 10) {
        float s = fb3[t];
        for (int k = 0; k < 256; ++k) s += fw3[t * 256 + k] * xa[k];
        lg[t] = s;
    }
    __syncthreads();
    if (t == 0) {
        float m = lg[0];
        for (int i = 1; i < 10; ++i) m = fmaxf(m, lg[i]);
        float s = 0.f;
        for (int i = 0; i < 10; ++i) s += expf(lg[i] - m);
        float ls = m + logf(s);
        for (int i = 0; i < 10; ++i) out[b * 10 + i] = lg[i] - ls;
    }
}

// ---------------- launch ----------------
extern "C" void kernel_launch(void* const* d_in, const int* in_sizes, int n_in,
                              void* d_out, int out_size, void* d_ws, size_t ws_size,
                              hipStream_t stream)
{
    (void)in_sizes; (void)n_in; (void)out_size; (void)ws_size;
    const float* img  = (const float*)d_in[0];
    const float* qst  = (const float*)d_in[1];
    const float* c1w  = (const float*)d_in[2];
    const float* c1b  = (const float*)d_in[3];
    const float* bn1g = (const float*)d_in[4];
    const float* bn1b = (const float*)d_in[5];
    const float* c2w  = (const float*)d_in[6];
    const float* c2b  = (const float*)d_in[7];
    const float* bn2g = (const float*)d_in[8];
    const float* bn2b = (const float*)d_in[9];
    const float* c3w  = (const float*)d_in[10];
    const float* c3b  = (const float*)d_in[11];
    const float* bn3g = (const float*)d_in[12];
    const float* bn3b = (const float*)d_in[13];
    const float* c4w  = (const float*)d_in[14];
    const float* c4b  = (const float*)d_in[15];
    const float* bn4g = (const float*)d_in[16];
    const float* bn4b = (const float*)d_in[17];
    const float* gw1  = (const float*)d_in[18];
    const float* gb1  = (const float*)d_in[19];
    const float* gw2  = (const float*)d_in[20];
    const float* gb2  = (const float*)d_in[21];
    const float* gw3  = (const float*)d_in[22];
    const float* gb3  = (const float*)d_in[23];
    const float* gw4  = (const float*)d_in[24];
    const float* gb4  = (const float*)d_in[25];
    const float* fw1  = (const float*)d_in[26];
    const float* fb1  = (const float*)d_in[27];
    const float* fw2  = (const float*)d_in[28];
    const float* fb2  = (const float*)d_in[29];
    const float* fw3  = (const float*)d_in[30];
    const float* fb3  = (const float*)d_in[31];

    const int Y1 = 512 * 24 * 38 * 38;
    const int Y2 = 512 * 24 * 19 * 19;
    const int Y3 = 512 * 24 * 10 * 10;
    const int Y4 = 512 * 24 * 5 * 5;

    // stats in DOUBLE at the head of ws (8B-aligned); everything else after
    double* stats = (double*)d_ws;       // [4 layers][24 ch][sum, sumsq] = 192 doubles
    float* fp = (float*)(stats + 192);
    float* y1    = fp;  fp += Y1;
    float* y2    = fp;  fp += Y2;
    float* y3    = fp;  fp += Y3;
    float* y4    = fp;  fp += Y4;
    float* xg5   = fp;  fp += 512 * GT_PER_B * 256;   // per-tile partial sums (no atomics)
    float* fw1T  = fp;  fp += 65536;
    float* fw2T  = fp;  fp += 65536;
    float* wT1   = fp;  fp += 648;       // conv weights transposed [k][24]
    float* wT2   = fp;  fp += 5184;
    float* wT3   = fp;  fp += 5184;
    float* wT4   = fp;  fp += 5184;
    bf16_t* bp   = (bf16_t*)fp;
    bf16_t* xf26 = bp;  bp += 512 * 25 * 26;
    bf16_t* qstb = bp;  bp += 512 * 11;
    bf16_t* W1f  = bp;  bp += 16384;     // g-weights in MFMA frag order
    bf16_t* W2f  = bp;  bp += 65536;
    bf16_t* W3f  = bp;  bp += 65536;
    bf16_t* W4f  = bp;  bp += 65536;

    hipMemsetAsync(stats, 0, 192 * sizeof(double), stream);

    // grid MUST cover all 360,264 work items (ceil -> 1408 blocks)
    prep_weights<<<1408, 256, 0, stream>>>(gw1, gw2, gw3, gw4, fw1, fw2, c1w, c2w, c3w, c4w,
                                           W1f, W2f, W3f, W4f, fw1T, fw2T,
                                           wT1, wT2, wT3, wT4);

    // conv1: 4 row-tiles of 10 per image, 384-thread blocks (6 waves x 4 co)
    conv1_bn<<<2048, 384, 0, stream>>>(img, wT1, c1b, y1, stats + 0);

    // conv2: 2 row-tiles of 10, 3 staging phases of 8 ch, 384thr (CPW=4) -> 24 waves/CU
    conv24_bn<38, 38, 19, 19, 10, 3, 8, 24, 384><<<1024, 384, 0, stream>>>(
        y1, wT2, c2b, stats + 0, bn1g, bn1b, 1.f / (512.f * 1444.f),
        y2, stats + 48, 2);

    // conv3: co-split (12 co per block), 384thr (CPW=2) -> 24 waves/CU
    conv24_bn<19, 19, 10, 10, 10, 2, 12, 12, 384><<<1024, 384, 0, stream>>>(
        y2, wT3, c3b, stats + 48, bn2g, bn2b, 1.f / (512.f * 361.f),
        y3, stats + 96, 1);

    // conv4: co-split (12 co per block), 384thr (CPW=2)
    conv24_bn<10, 10, 5, 5, 5, 1, 12, 12, 384><<<1024, 384, 0, stream>>>(
        y3, wT4, c4b, stats + 96, bn3g, bn3b, 1.f / (512.f * 100.f),
        y4, stats + 144, 1);

    build_features<<<50, 256, 0, stream>>>(y4, stats + 144, bn4g, bn4b, qst, xf26, qstb);

    g_mlp<<<512 * GT_PER_B, 256, 0, stream>>>(xf26, qstb, W1f, W2f, W3f, W4f,
                                              gb1, gb2, gb3, gb4, xg5);

    f_mlp<<<512, 256, 0, stream>>>(xg5, fw1T, fb1, fw2T, fb2, fw3, fb3, (float*)d_out);
}

// Round 12
// 533.360 us; speedup vs baseline: 1.0258x; 1.0242x over previous
//
#include <hip/hip_runtime.h>

typedef __bf16 bf16_t;
typedef __bf16 bf16x8 __attribute__((ext_vector_type(8)));
typedef __bf16 bf16x4 __attribute__((ext_vector_type(4)));
typedef float f32x16 __attribute__((ext_vector_type(16)));

#define MB 512
#define GROWS 128     // pair rows per g-block (4 mtiles of 32)
#define GT_PER_B 5    // ceil(625/128)

// ================= conv1: CIN=3, 75x75 -> 38x38 ============
// Round-12: REVERT to round-9 (measured best, 534us). r10/r11's row-loop staging was a
// -12us regression (concentrated staging in 231/384 threads -> lost memory-level
// parallelism); the strided element loop below spreads loads over all 384 lanes.
// 384-thread blocks (6 waves, 4 co/wave), LDS 19.4KB, 5 blocks/CU = 30 waves.
// Stats in f64 atomics (fp32 atomic-order jitter caused the round-1 divergence).
__global__ __launch_bounds__(384, 6) void conv1_bn(const float* __restrict__ img,
                                                   const float* __restrict__ wT,
                                                   const float* __restrict__ bias,
                                                   float* __restrict__ out,
                                                   double* __restrict__ statsOut)
{
    __shared__ float in_s[3 * 21 * 77];   // 19,404 B
    __shared__ float red[48];
    int bid = blockIdx.x;
    int n = bid >> 2, tile = bid & 3;
    int oh0 = tile * 10;
    int tid = threadIdx.x;

    for (int idx = tid; idx < 3 * 21 * 77; idx += 384) {
        int ci = idx / (21 * 77);
        int rem = idx - ci * (21 * 77);
        int r = rem / 77, c = rem - r * 77;
        int ih = 2 * oh0 - 1 + r, iw = c - 1;
        float v = 0.f;
        if ((unsigned)ih < 75u && (unsigned)iw < 75u)
            v = img[((n * 3 + ci) * 75 + ih) * 75 + iw];
        in_s[idx] = v;
    }
    __syncthreads();

    int cg = tid >> 6, lane = tid & 63, co0 = cg * 4;   // 6 waves x 4 co
    int nvr = 38 - oh0; if (nvr > 10) nvr = 10;
    int nposv = nvr * 38;
    int off[6];
    bool pv[6];
#pragma unroll
    for (int j = 0; j < 6; ++j) {
        int p = lane + j * 64;
        pv[j] = p < nposv;
        int pc = pv[j] ? p : 0;
        int r0 = pc / 38, c0 = pc - r0 * 38;
        off[j] = (r0 * 2) * 77 + c0 * 2;
    }
    float acc[4][6];
#pragma unroll
    for (int c = 0; c < 4; ++c)
#pragma unroll
        for (int j = 0; j < 6; ++j) acc[c][j] = 0.f;

#pragma unroll 1
    for (int ci = 0; ci < 3; ++ci) {
        const float* ip = in_s + ci * (21 * 77);
        const float* wp = wT + ci * 9 * 24 + co0;
#pragma unroll
        for (int kh = 0; kh < 3; ++kh) {
#pragma unroll
            for (int kw = 0; kw < 3; ++kw) {
                float iv[6];
#pragma unroll
                for (int j = 0; j < 6; ++j) iv[j] = ip[off[j] + kh * 77 + kw];
                const float* wr = wp + (kh * 3 + kw) * 24;
                float2 w01 = *(const float2*)(wr);
                float2 w23 = *(const float2*)(wr + 2);
#pragma unroll
                for (int j = 0; j < 6; ++j) {
                    acc[0][j] = fmaf(iv[j], w01.x, acc[0][j]);
                    acc[1][j] = fmaf(iv[j], w01.y, acc[1][j]);
                    acc[2][j] = fmaf(iv[j], w23.x, acc[2][j]);
                    acc[3][j] = fmaf(iv[j], w23.y, acc[3][j]);
                }
            }
        }
    }

    float sst[4], sq[4];
#pragma unroll
    for (int c = 0; c < 4; ++c) { sst[c] = 0.f; sq[c] = 0.f; }
#pragma unroll
    for (int c = 0; c < 4; ++c) {
        float bv = bias[co0 + c];
#pragma unroll
        for (int j = 0; j < 6; ++j) {
            if (pv[j]) {
                int p = lane + j * 64;
                int r = p / 38, q = p - r * 38;
                float v = fmaxf(acc[c][j] + bv, 0.f);
                out[((n * 24 + co0 + c) * 38 + oh0 + r) * 38 + q] = v;
                sst[c] += v; sq[c] += v * v;
            }
        }
    }
#pragma unroll
    for (int o = 1; o < 64; o <<= 1) {
#pragma unroll
        for (int c = 0; c < 4; ++c) {
            sst[c] += __shfl_xor(sst[c], o);
            sq[c]  += __shfl_xor(sq[c], o);
        }
    }
    if (lane == 0) {
#pragma unroll
        for (int c = 0; c < 4; ++c) {
            red[(co0 + c) * 2]     = sst[c];
            red[(co0 + c) * 2 + 1] = sq[c];
        }
    }
    __syncthreads();
    if (tid < 48) atomicAdd(&statsOut[tid], (double)red[tid]);
}

// ============ conv2/3/4: CIN=24, staged in 24/CIB phases; COB co per block; NT threads ==
// Round-12: REVERT to round-9 strided staging (spreads loads over all NT lanes — max
// memory-level parallelism; the r10/r11 row-loop variant cost +12us). NT=384 (6 waves),
// 4 blocks/CU = 24 waves/CU, zero staging redundancy, 85-VGPR cap. CPW = COB/(NT/64).
// ci summation order 0..23 ascending; stats f64-atomic (replay-stable).
template <int HIN, int WIN, int HOUT, int WOUT, int OHT, int NP, int CIB, int COB, int NT>
__global__ __launch_bounds__(NT, 6) void conv24_bn(const float* __restrict__ in,
                                                   const float* __restrict__ wT,
                                                   const float* __restrict__ bias,
                                                   const double* __restrict__ statsIn,
                                                   const float* __restrict__ gIn,
                                                   const float* __restrict__ bIn, float invcntIn,
                                                   float* __restrict__ out,
                                                   double* __restrict__ statsOut, int tilesPerImg)
{
    constexpr int IR = 2 * OHT + 1;
    constexpr int ICW = 2 * WOUT + 1;
    constexpr int NPH = 24 / CIB;
    constexpr int NCO = 24 / COB;      // co-groups per image-tile
    constexpr int NW  = NT / 64;       // waves per block
    constexpr int CPW = COB / NW;      // co per wave (6/4/3/2)
    __shared__ float in_s[CIB * IR * ICW];
    __shared__ float aff[48];
    __shared__ float red[48];

    int bid = blockIdx.x;
    int n = bid / (tilesPerImg * NCO);
    int rem = bid - n * (tilesPerImg * NCO);
    int tile = rem / NCO;
    int coBase = (rem - tile * NCO) * COB;
    int oh0 = tile * OHT;
    int tid = threadIdx.x;

    if (tid < 24) {
        double meand = statsIn[tid * 2] * (double)invcntIn;
        double vard  = statsIn[tid * 2 + 1] * (double)invcntIn - meand * meand;
        float mean = (float)meand;
        float s    = gIn[tid] * rsqrtf((float)vard + 1e-5f);
        aff[tid * 2] = s;
        aff[tid * 2 + 1] = bIn[tid] - mean * s;
    }
    __syncthreads();

    int cg = tid >> 6, lane = tid & 63, co0 = coBase + cg * CPW;
    int nvr = HOUT - oh0; if (nvr > OHT) nvr = OHT;
    int nposv = nvr * WOUT;
    int off[NP];
    bool pv[NP];
#pragma unroll
    for (int j = 0; j < NP; ++j) {
        int p = lane + j * 64;
        pv[j] = p < nposv;
        int pc = pv[j] ? p : 0;
        int r0 = pc / WOUT, c0 = pc - r0 * WOUT;
        off[j] = (r0 * 2) * ICW + c0 * 2;
    }
    float acc[CPW][NP];
#pragma unroll
    for (int c = 0; c < CPW; ++c)
#pragma unroll
        for (int j = 0; j < NP; ++j) acc[c][j] = 0.f;

#pragma unroll 1
    for (int ph = 0; ph < NPH; ++ph) {
        if (ph) __syncthreads();   // all waves done reading previous phase's LDS
        for (int idx = tid; idx < CIB * IR * ICW; idx += NT) {
            int ci = idx / (IR * ICW);
            int rem2 = idx - ci * (IR * ICW);
            int r = rem2 / ICW, c = rem2 - r * ICW;
            int gci = ph * CIB + ci;
            int ih = 2 * oh0 - 1 + r, iw = c - 1;
            float v = 0.f;
            if ((unsigned)ih < (unsigned)HIN && (unsigned)iw < (unsigned)WIN)
                v = aff[gci * 2] * in[((n * 24 + gci) * HIN + ih) * WIN + iw] + aff[gci * 2 + 1];
            in_s[idx] = v;
        }
        __syncthreads();

#pragma unroll 1
        for (int ci = 0; ci < CIB; ++ci) {
            const float* ip = in_s + ci * (IR * ICW);
            const float* wp = wT + (ph * CIB + ci) * 9 * 24 + co0;
#pragma unroll
            for (int kh = 0; kh < 3; ++kh) {
#pragma unroll
                for (int kw = 0; kw < 3; ++kw) {
                    float iv[NP];
#pragma unroll
                    for (int j = 0; j < NP; ++j) iv[j] = ip[off[j] + kh * ICW + kw];
                    const float* wr = wp + (kh * 3 + kw) * 24;
                    if constexpr (CPW == 6) {
                        float2 w01 = *(const float2*)(wr);
                        float2 w23 = *(const float2*)(wr + 2);
                        float2 w45 = *(const float2*)(wr + 4);
#pragma unroll
                        for (int j = 0; j < NP; ++j) {
                            acc[0][j] = fmaf(iv[j], w01.x, acc[0][j]);
                            acc[1][j] = fmaf(iv[j], w01.y, acc[1][j]);
                            acc[2][j] = fmaf(iv[j], w23.x, acc[2][j]);
                            acc[3][j] = fmaf(iv[j], w23.y, acc[3][j]);
                            acc[4][j] = fmaf(iv[j], w45.x, acc[4][j]);
                            acc[5][j] = fmaf(iv[j], w45.y, acc[5][j]);
                        }
                    } else if constexpr (CPW == 4) {
                        float2 w01 = *(const float2*)(wr);
                        float2 w23 = *(const float2*)(wr + 2);
#pragma unroll
                        for (int j = 0; j < NP; ++j) {
                            acc[0][j] = fmaf(iv[j], w01.x, acc[0][j]);
                            acc[1][j] = fmaf(iv[j], w01.y, acc[1][j]);
                            acc[2][j] = fmaf(iv[j], w23.x, acc[2][j]);
                            acc[3][j] = fmaf(iv[j], w23.y, acc[3][j]);
                        }
                    } else if constexpr (CPW == 3) {
                        float w0 = wr[0], w1 = wr[1], w2 = wr[2];
#pragma unroll
                        for (int j = 0; j < NP; ++j) {
                            acc[0][j] = fmaf(iv[j], w0, acc[0][j]);
                            acc[1][j] = fmaf(iv[j], w1, acc[1][j]);
                            acc[2][j] = fmaf(iv[j], w2, acc[2][j]);
                        }
                    } else {   // CPW == 2
                        float2 w01 = *(const float2*)(wr);
#pragma unroll
                        for (int j = 0; j < NP; ++j) {
                            acc[0][j] = fmaf(iv[j], w01.x, acc[0][j]);
                            acc[1][j] = fmaf(iv[j], w01.y, acc[1][j]);
                        }
                    }
                }
            }
        }
    }

    float sst[CPW], sq[CPW];
#pragma unroll
    for (int c = 0; c < CPW; ++c) { sst[c] = 0.f; sq[c] = 0.f; }
#pragma unroll
    for (int c = 0; c < CPW; ++c) {
        float bv = bias[co0 + c];
#pragma unroll
        for (int j = 0; j < NP; ++j) {
            if (pv[j]) {
                int p = lane + j * 64;
                int r = p / WOUT, q = p - r * WOUT;
                float v = fmaxf(acc[c][j] + bv, 0.f);
                out[((n * 24 + co0 + c) * HOUT + oh0 + r) * WOUT + q] = v;
                sst[c] += v; sq[c] += v * v;
            }
        }
    }
#pragma unroll
    for (int o = 1; o < 64; o <<= 1) {
#pragma unroll
        for (int c = 0; c < CPW; ++c) {
            sst[c] += __shfl_xor(sst[c], o);
            sq[c]  += __shfl_xor(sq[c], o);
        }
    }
    if (lane == 0) {
#pragma unroll
        for (int c = 0; c < CPW; ++c) {
            int lc = cg * CPW + c;   // local channel within this block's COB
            red[lc * 2]     = sst[c];
            red[lc * 2 + 1] = sq[c];
        }
    }
    __syncthreads();
    if (tid < COB * 2) atomicAdd(&statsOut[coBase * 2 + tid], (double)red[tid]);
}

// ---------------- build bf16 features: xf26 = [BN4(conv4) 24ch, coords 2] ; qst bf16 ----------------
__global__ void build_features(const float* __restrict__ y4, const double* __restrict__ stats4,
                               const float* __restrict__ g4, const float* __restrict__ b4,
                               const float* __restrict__ qst,
                               bf16_t* __restrict__ xf26, bf16_t* __restrict__ qstb)
{
    int idx = blockIdx.x * 256 + threadIdx.x;
    if (idx < MB * 11) qstb[idx] = (bf16_t)qst[idx];
    if (idx >= MB * 25) return;
    int b = idx / 25, p = idx % 25;
    const double invcnt = 1.0 / (MB * 25);
#pragma unroll
    for (int ch = 0; ch < 24; ++ch) {
        double meand = stats4[ch * 2] * invcnt;
        double vard  = stats4[ch * 2 + 1] * invcnt - meand * meand;
        float mean = (float)meand;
        float s    = g4[ch] * rsqrtf((float)vard + 1e-5f);
        float v    = s * y4[(b * 24 + ch) * 25 + p] + (b4[ch] - mean * s);
        xf26[idx * 26 + ch] = (bf16_t)v;
    }
    xf26[idx * 26 + 24] = (bf16_t)((p / 5.0f - 2.0f) * 0.5f);
    xf26[idx * 26 + 25] = (bf16_t)(((float)(p % 5) - 2.0f) * 0.5f);
}

// ------- weight prep: g-weights in MFMA-A-frag order, fp32 transposes for f-MLP, conv wT --------
// Wf layout per layer: [nt (N/32)][ks (K/16)][lane 0..63][j 0..7]
//   element = W[nt*32 + (lane&31)][ks*16 + (lane>>5)*8 + j]
__device__ __forceinline__ void frag256(int idx, const float* __restrict__ gw, bf16_t* __restrict__ Wf)
{
    int j = idx & 7, lane = (idx >> 3) & 63, ks = (idx >> 9) & 15, nt = idx >> 13;
    int n = nt * 32 + (lane & 31), k = ks * 16 + (lane >> 5) * 8 + j;
    Wf[idx] = (bf16_t)gw[n * 256 + k];
}

// total work items: 16384 + 3*65536 + 2*65536 + 648 + 3*5184 = 360,264 -> grid 1408x256 = 360,448
__global__ void prep_weights(const float* __restrict__ gw1, const float* __restrict__ gw2,
                             const float* __restrict__ gw3, const float* __restrict__ gw4,
                             const float* __restrict__ fw1, const float* __restrict__ fw2,
                             const float* __restrict__ c1w, const float* __restrict__ c2w,
                             const float* __restrict__ c3w, const float* __restrict__ c4w,
                             bf16_t* __restrict__ W1f, bf16_t* __restrict__ W2f,
                             bf16_t* __restrict__ W3f, bf16_t* __restrict__ W4f,
                             float* __restrict__ fw1T, float* __restrict__ fw2T,
                             float* __restrict__ wT1, float* __restrict__ wT2,
                             float* __restrict__ wT3, float* __restrict__ wT4)
{
    int idx = blockIdx.x * 256 + threadIdx.x;
    if (idx < 16384) {  // W1: K=64 (63 + zero pad), [8 nt][4 ks][64][8]
        int j = idx & 7, lane = (idx >> 3) & 63, ks = (idx >> 9) & 3, nt = idx >> 11;
        int n = nt * 32 + (lane & 31), k = ks * 16 + (lane >> 5) * 8 + j;
        W1f[idx] = (k < 63) ? (bf16_t)gw1[n * 63 + k] : (bf16_t)0.0f;
        return;
    }
    idx -= 16384;
    if (idx < 65536) { frag256(idx, gw2, W2f); return; }
    idx -= 65536;
    if (idx < 65536) { frag256(idx, gw3, W3f); return; }
    idx -= 65536;
    if (idx < 65536) { frag256(idx, gw4, W4f); return; }
    idx -= 65536;
    if (idx < 65536) { int k = idx >> 8, nn = idx & 255; fw1T[idx] = fw1[nn * 256 + k]; return; }
    idx -= 65536;
    if (idx < 65536) { int k = idx >> 8, nn = idx & 255; fw2T[idx] = fw2[nn * 256 + k]; return; }
    idx -= 65536;
    if (idx < 648)   { int k = idx / 24, co = idx - k * 24; wT1[idx] = c1w[co * 27 + k]; return; }
    idx -= 648;
    if (idx < 5184)  { int k = idx / 24, co = idx - k * 24; wT2[idx] = c2w[co * 216 + k]; return; }
    idx -= 5184;
    if (idx < 5184)  { int k = idx / 24, co = idx - k * 24; wT3[idx] = c3w[co * 216 + k]; return; }
    idx -= 5184;
    if (idx < 5184)  { int k = idx / 24, co = idx - k * 24; wT4[idx] = c4w[co * 216 + k]; return; }
}

// ---------------- fused g-MLP: 32x32x16 MFMA, swapped operands (A=W, B=h^T), swizzled LDS ----------------
// Round-12: round-9 body (no setprio — r8 A/B showed it regresses this lockstep kernel;
// no hf-dbuf — r10 A/B showed null). Pinned at ~153us / MfmaUtil 40% across 7 variants;
// breaking it needs the counted-vmcnt 8-phase treatment — out of polish-session scope.

template <int NKS>
__device__ __forceinline__ void g_quarter(const bf16_t* hs, const bf16_t* __restrict__ wbase0,
                                          const bf16_t* __restrict__ wbase1,
                                          int q, int m31, int half,
                                          bf16x8 (&CUR)[2][4], bf16x8 (&NXT)[2][4],
                                          f32x16 (&acc)[4][2])
{
    if (q + 1 < NKS / 4) {   // prefetch next quarter's wf while this quarter's MFMAs run
#pragma unroll
        for (int k = 0; k < 4; ++k) {
            NXT[0][k] = *(const bf16x8*)(wbase0 + (size_t)((q + 1) * 4 + k) * 512);
            NXT[1][k] = *(const bf16x8*)(wbase1 + (size_t)((q + 1) * 4 + k) * 512);
        }
    }
#pragma unroll
    for (int kk = 0; kk < 4; ++kk) {
        int ks = q * 4 + kk;
        int kc = ks * 2 + half;
        bf16x8 hf[4];
#pragma unroll
        for (int mt = 0; mt < 4; ++mt) {
            int m = mt * 32 + m31;
            hf[mt] = *(const bf16x8*)(hs + m * 256 + ((kc ^ m31) << 3));
        }
#pragma unroll
        for (int mt = 0; mt < 4; ++mt) {
            acc[mt][0] = __builtin_amdgcn_mfma_f32_32x32x16_bf16(CUR[0][kk], hf[mt], acc[mt][0], 0, 0, 0);
            acc[mt][1] = __builtin_amdgcn_mfma_f32_32x32x16_bf16(CUR[1][kk], hf[mt], acc[mt][1], 0, 0, 0);
        }
    }
}

template <int NKS>  // K/16: 4 for layer1, 16 for layers 2-4
__device__ __forceinline__ void g_layer(const bf16_t* hs, const bf16_t* __restrict__ Wf,
                                        int wid, int lane, f32x16 (&acc)[4][2])
{
    int m31 = lane & 31, half = lane >> 5;
#pragma unroll
    for (int mt = 0; mt < 4; ++mt)
#pragma unroll
        for (int nt = 0; nt < 2; ++nt) acc[mt][nt] = (f32x16)(0.f);

    const bf16_t* wbase0 = Wf + (size_t)(((wid * 2 + 0) * NKS) * 64 + lane) * 8;
    const bf16_t* wbase1 = Wf + (size_t)(((wid * 2 + 1) * NKS) * 64 + lane) * 8;
    bf16x8 wA[2][4], wB[2][4];
#pragma unroll
    for (int k = 0; k < 4; ++k) {   // preload quarter 0
        wA[0][k] = *(const bf16x8*)(wbase0 + (size_t)k * 512);
        wA[1][k] = *(const bf16x8*)(wbase1 + (size_t)k * 512);
    }
#pragma unroll
    for (int q = 0; q < NKS / 4; ++q) {
        if ((q & 1) == 0) g_quarter<NKS>(hs, wbase0, wbase1, q, m31, half, wA, wB, acc);
        else              g_quarter<NKS>(hs, wbase0, wbase1, q, m31, half, wB, wA, acc);
    }
}

__device__ __forceinline__ void g_store(bf16_t* hs, const float* __restrict__ bias,
                                        int wid, int lane, f32x16 (&acc)[4][2])
{
    int m31 = lane & 31, half = lane >> 5;
#pragma unroll
    for (int mt = 0; mt < 4; ++mt) {
        int m = mt * 32 + m31;
#pragma unroll
        for (int nt = 0; nt < 2; ++nt) {
            int nbase = (wid * 2 + nt) * 32;
#pragma unroll
            for (int g = 0; g < 4; ++g) {
                int n0 = nbase + g * 8 + half * 4;
                float4 bv = *(const float4*)(bias + n0);
                bf16x4 v;
                v[0] = (bf16_t)fmaxf(acc[mt][nt][g * 4 + 0] + bv.x, 0.f);
                v[1] = (bf16_t)fmaxf(acc[mt][nt][g * 4 + 1] + bv.y, 0.f);
                v[2] = (bf16_t)fmaxf(acc[mt][nt][g * 4 + 2] + bv.z, 0.f);
                v[3] = (bf16_t)fmaxf(acc[mt][nt][g * 4 + 3] + bv.w, 0.f);
                int chunk = n0 >> 3;  // half*4 < 8, so chunk = (nbase + g*8) >> 3
                *(bf16x4*)(hs + m * 256 + ((chunk ^ m31) << 3) + (half << 2)) = v;
            }
        }
    }
}

__global__ void __launch_bounds__(256, 2)
g_mlp(const bf16_t* __restrict__ xf26, const bf16_t* __restrict__ qstb,
      const bf16_t* __restrict__ W1f, const bf16_t* __restrict__ W2f,
      const bf16_t* __restrict__ W3f, const bf16_t* __restrict__ W4f,
      const float* __restrict__ b1, const float* __restrict__ b2,
      const float* __restrict__ b3, const float* __restrict__ b4,
      float* __restrict__ xg5)
{
    __shared__ __align__(16) bf16_t hs[GROWS * 256];   // 65,536 B
    int b    = blockIdx.x / GT_PER_B;
    int tile = blockIdx.x % GT_PER_B;
    int tid  = threadIdx.x;

    // stage features (64 bf16 per row -> chunks 0..7, swizzled)
    for (int i = tid; i < GROWS * 8; i += 256) {
        int m = i >> 3, c = i & 7;
        int p = tile * GROWS + m;
        bf16x8 v;
        if (p < 625) {
            int a = p / 25, cp = p - a * 25;
            const bf16_t* f1 = xf26 + (b * 25 + cp) * 26;
            const bf16_t* f2 = xf26 + (b * 25 + a) * 26;
            const bf16_t* f3 = qstb + b * 11;
#pragma unroll
            for (int j = 0; j < 8; ++j) {
                int col = c * 8 + j;
                bf16_t u = (bf16_t)0.0f;
                if (col < 26) u = f1[col];
                else if (col < 52) u = f2[col - 26];
                else if (col < 63) u = f3[col - 52];
                v[j] = u;
            }
        } else {
#pragma unroll
            for (int j = 0; j < 8; ++j) v[j] = (bf16_t)0.0f;
        }
        *(bf16x8*)(hs + m * 256 + ((c ^ (m & 31)) << 3)) = v;
    }
    __syncthreads();

    int wid = tid >> 6, lane = tid & 63;
    int m31 = lane & 31, half = lane >> 5;
    f32x16 acc[4][2];

    g_layer<4>(hs, W1f, wid, lane, acc);
    __syncthreads(); g_store(hs, b1, wid, lane, acc); __syncthreads();
    g_layer<16>(hs, W2f, wid, lane, acc);
    __syncthreads(); g_store(hs, b2, wid, lane, acc); __syncthreads();
    g_layer<16>(hs, W3f, wid, lane, acc);
    __syncthreads(); g_store(hs, b3, wid, lane, acc); __syncthreads();
    g_layer<16>(hs, W4f, wid, lane, acc);

    // epilogue: relu(acc + b4), mask invalid rows, sum over m, plain store into xg5 slot
#pragma unroll
    for (int nt = 0; nt < 2; ++nt) {
        int nbase = (wid * 2 + nt) * 32;
        float bf[16];
#pragma unroll
        for (int r = 0; r < 16; ++r)
            bf[r] = b4[nbase + (r & 3) + 8 * (r >> 2) + 4 * half];
        f32x16 t = (f32x16)(0.f);
#pragma unroll
        for (int mt = 0; mt < 4; ++mt) {
            int p = tile * GROWS + mt * 32 + m31;
            if (p < 625) {
#pragma unroll
                for (int r = 0; r < 16; ++r)
                    t[r] += fmaxf(acc[mt][nt][r] + bf[r], 0.f);
            }
        }
#pragma unroll
        for (int off = 1; off < 32; off <<= 1) {
#pragma unroll
            for (int r = 0; r < 16; ++r) t[r] += __shfl_xor(t[r], off);
        }
        if (m31 == 0) {
#pragma unroll
            for (int r = 0; r < 16; ++r) {
                int nn = nbase + (r & 3) + 8 * (r >> 2) + 4 * half;
                xg5[(b * GT_PER_B + tile) * 256 + nn] = t[r];
            }
        }
    }
}

// ---------------- f-MLP (fp32) + log_softmax, one block per batch element ----------------
// Sums the 5 per-tile g_mlp slots (replaces global atomics).
__global__ void f_mlp(const float* __restrict__ xg5, const float* __restrict__ fw1T, const float* __restrict__ fb1,
                      const float* __restrict__ fw2T, const float* __restrict__ fb2,
                      const float* __restrict__ fw3, const float* __restrict__ fb3,
                      float* __restrict__ out)
{
    __shared__ float xa[256], xb[256], lg[10];
    int b = blockIdx.x, t = threadIdx.x;
    float s0 = 0.f;
#pragma unroll
    for (int i = 0; i < GT_PER_B; ++i) s0 += xg5[(b * GT_PER_B + i) * 256 + t];
    xa[t] = s0;
    __syncthreads();
    float a = fb1[t];
    for (int k = 0; k < 256; ++k) a += fw1T[k * 256 + t] * xa[k];
    xb[t] = fmaxf(a, 0.f);
    __syncthreads();
    a = fb2[t];
    for (int k = 0; k < 256; ++k) a += fw2T[k * 256 + t] * xb[k];
    xa[t] = fmaxf(a, 0.f);
    __syncthreads();
    if (t < 10) {
        float s = fb3[t];
        for (int k = 0; k < 256; ++k) s += fw3[t * 256 + k] * xa[k];
        lg[t] = s;
    }
    __syncthreads();
    if (t == 0) {
        float m = lg[0];
        for (int i = 1; i < 10; ++i) m = fmaxf(m, lg[i]);
        float s = 0.f;
        for (int i = 0; i < 10; ++i) s += expf(lg[i] - m);
        float ls = m + logf(s);
        for (int i = 0; i < 10; ++i) out[b * 10 + i] = lg[i] - ls;
    }
}

// ---------------- launch ----------------
extern "C" void kernel_launch(void* const* d_in, const int* in_sizes, int n_in,
                              void* d_out, int out_size, void* d_ws, size_t ws_size,
                              hipStream_t stream)
{
    (void)in_sizes; (void)n_in; (void)out_size; (void)ws_size;
    const float* img  = (const float*)d_in[0];
    const float* qst  = (const float*)d_in[1];
    const float* c1w  = (const float*)d_in[2];
    const float* c1b  = (const float*)d_in[3];
    const float* bn1g = (const float*)d_in[4];
    const float* bn1b = (const float*)d_in[5];
    const float* c2w  = (const float*)d_in[6];
    const float* c2b  = (const float*)d_in[7];
    const float* bn2g = (const float*)d_in[8];
    const float* bn2b = (const float*)d_in[9];
    const float* c3w  = (const float*)d_in[10];
    const float* c3b  = (const float*)d_in[11];
    const float* bn3g = (const float*)d_in[12];
    const float* bn3b = (const float*)d_in[13];
    const float* c4w  = (const float*)d_in[14];
    const float* c4b  = (const float*)d_in[15];
    const float* bn4g = (const float*)d_in[16];
    const float* bn4b = (const float*)d_in[17];
    const float* gw1  = (const float*)d_in[18];
    const float* gb1  = (const float*)d_in[19];
    const float* gw2  = (const float*)d_in[20];
    const float* gb2  = (const float*)d_in[21];
    const float* gw3  = (const float*)d_in[22];
    const float* gb3  = (const float*)d_in[23];
    const float* gw4  = (const float*)d_in[24];
    const float* gb4  = (const float*)d_in[25];
    const float* fw1  = (const float*)d_in[26];
    const float* fb1  = (const float*)d_in[27];
    const float* fw2  = (const float*)d_in[28];
    const float* fb2  = (const float*)d_in[29];
    const float* fw3  = (const float*)d_in[30];
    const float* fb3  = (const float*)d_in[31];

    const int Y1 = 512 * 24 * 38 * 38;
    const int Y2 = 512 * 24 * 19 * 19;
    const int Y3 = 512 * 24 * 10 * 10;
    const int Y4 = 512 * 24 * 5 * 5;

    // stats in DOUBLE at the head of ws (8B-aligned); everything else after
    double* stats = (double*)d_ws;       // [4 layers][24 ch][sum, sumsq] = 192 doubles
    float* fp = (float*)(stats + 192);
    float* y1    = fp;  fp += Y1;
    float* y2    = fp;  fp += Y2;
    float* y3    = fp;  fp += Y3;
    float* y4    = fp;  fp += Y4;
    float* xg5   = fp;  fp += 512 * GT_PER_B * 256;   // per-tile partial sums (no atomics)
    float* fw1T  = fp;  fp += 65536;
    float* fw2T  = fp;  fp += 65536;
    float* wT1   = fp;  fp += 648;       // conv weights transposed [k][24]
    float* wT2   = fp;  fp += 5184;
    float* wT3   = fp;  fp += 5184;
    float* wT4   = fp;  fp += 5184;
    bf16_t* bp   = (bf16_t*)fp;
    bf16_t* xf26 = bp;  bp += 512 * 25 * 26;
    bf16_t* qstb = bp;  bp += 512 * 11;
    bf16_t* W1f  = bp;  bp += 16384;     // g-weights in MFMA frag order
    bf16_t* W2f  = bp;  bp += 65536;
    bf16_t* W3f  = bp;  bp += 65536;
    bf16_t* W4f  = bp;  bp += 65536;

    hipMemsetAsync(stats, 0, 192 * sizeof(double), stream);

    // grid MUST cover all 360,264 work items (ceil -> 1408 blocks)
    prep_weights<<<1408, 256, 0, stream>>>(gw1, gw2, gw3, gw4, fw1, fw2, c1w, c2w, c3w, c4w,
                                           W1f, W2f, W3f, W4f, fw1T, fw2T,
                                           wT1, wT2, wT3, wT4);

    // conv1: 4 row-tiles of 10 per image, 384-thread blocks (6 waves x 4 co)
    conv1_bn<<<2048, 384, 0, stream>>>(img, wT1, c1b, y1, stats + 0);

    // conv2: 2 row-tiles of 10, 3 staging phases of 8 ch, 384thr (CPW=4) -> 24 waves/CU
    conv24_bn<38, 38, 19, 19, 10, 3, 8, 24, 384><<<1024, 384, 0, stream>>>(
        y1, wT2, c2b, stats + 0, bn1g, bn1b, 1.f / (512.f * 1444.f),
        y2, stats + 48, 2);

    // conv3: co-split (12 co per block), 384thr (CPW=2) -> 24 waves/CU
    conv24_bn<19, 19, 10, 10, 10, 2, 12, 12, 384><<<1024, 384, 0, stream>>>(
        y2, wT3, c3b, stats + 48, bn2g, bn2b, 1.f / (512.f * 361.f),
        y3, stats + 96, 1);

    // conv4: co-split (12 co per block), 384thr (CPW=2)
    conv24_bn<10, 10, 5, 5, 5, 1, 12, 12, 384><<<1024, 384, 0, stream>>>(
        y3, wT4, c4b, stats + 96, bn3g, bn3b, 1.f / (512.f * 100.f),
        y4, stats + 144, 1);

    build_features<<<50, 256, 0, stream>>>(y4, stats + 144, bn4g, bn4b, qst, xf26, qstb);

    g_mlp<<<512 * GT_PER_B, 256, 0, stream>>>(xf26, qstb, W1f, W2f, W3f, W4f,
                                              gb1, gb2, gb3, gb4, xg5);

    f_mlp<<<512, 256, 0, stream>>>(xg5, fw1T, fb1, fw2T, fb2, fw3, fb3, (float*)d_out);
}

// Round 13
// 522.941 us; speedup vs baseline: 1.0462x; 1.0199x over previous
//
#include <hip/hip_runtime.h>

typedef __bf16 bf16_t;
typedef __bf16 bf16x8 __attribute__((ext_vector_type(8)));
typedef __bf16 bf16x4 __attribute__((ext_vector_type(4)));
typedef float f32x16 __attribute__((ext_vector_type(16)));

#define MB 512
#define GROWS 128     // pair rows per g-block (4 mtiles of 32)
#define GT_PER_B 5    // ceil(625/128)

// ================= conv1: CIN=3, 75x75 -> 38x38 ============
// r9-best body: strided element staging (spreads loads over all 384 lanes — the r10/r11
// row-loop variant cost +12us of lost memory-level parallelism). 384 thr (6 waves x 4 co),
// LDS 19.4KB, 5 blocks/CU = 30 waves. Stats in f64 atomics (fp32 atomic-order jitter
// caused the round-1 post-timing divergence).
__global__ __launch_bounds__(384, 6) void conv1_bn(const float* __restrict__ img,
                                                   const float* __restrict__ wT,
                                                   const float* __restrict__ bias,
                                                   float* __restrict__ out,
                                                   double* __restrict__ statsOut)
{
    __shared__ float in_s[3 * 21 * 77];   // 19,404 B
    __shared__ float red[48];
    int bid = blockIdx.x;
    int n = bid >> 2, tile = bid & 3;
    int oh0 = tile * 10;
    int tid = threadIdx.x;

    for (int idx = tid; idx < 3 * 21 * 77; idx += 384) {
        int ci = idx / (21 * 77);
        int rem = idx - ci * (21 * 77);
        int r = rem / 77, c = rem - r * 77;
        int ih = 2 * oh0 - 1 + r, iw = c - 1;
        float v = 0.f;
        if ((unsigned)ih < 75u && (unsigned)iw < 75u)
            v = img[((n * 3 + ci) * 75 + ih) * 75 + iw];
        in_s[idx] = v;
    }
    __syncthreads();

    int cg = tid >> 6, lane = tid & 63, co0 = cg * 4;   // 6 waves x 4 co
    int nvr = 38 - oh0; if (nvr > 10) nvr = 10;
    int nposv = nvr * 38;
    int off[6];
    bool pv[6];
#pragma unroll
    for (int j = 0; j < 6; ++j) {
        int p = lane + j * 64;
        pv[j] = p < nposv;
        int pc = pv[j] ? p : 0;
        int r0 = pc / 38, c0 = pc - r0 * 38;
        off[j] = (r0 * 2) * 77 + c0 * 2;
    }
    float acc[4][6];
#pragma unroll
    for (int c = 0; c < 4; ++c)
#pragma unroll
        for (int j = 0; j < 6; ++j) acc[c][j] = 0.f;

#pragma unroll 1
    for (int ci = 0; ci < 3; ++ci) {
        const float* ip = in_s + ci * (21 * 77);
        const float* wp = wT + ci * 9 * 24 + co0;
#pragma unroll
        for (int kh = 0; kh < 3; ++kh) {
#pragma unroll
            for (int kw = 0; kw < 3; ++kw) {
                float iv[6];
#pragma unroll
                for (int j = 0; j < 6; ++j) iv[j] = ip[off[j] + kh * 77 + kw];
                const float* wr = wp + (kh * 3 + kw) * 24;
                float2 w01 = *(const float2*)(wr);
                float2 w23 = *(const float2*)(wr + 2);
#pragma unroll
                for (int j = 0; j < 6; ++j) {
                    acc[0][j] = fmaf(iv[j], w01.x, acc[0][j]);
                    acc[1][j] = fmaf(iv[j], w01.y, acc[1][j]);
                    acc[2][j] = fmaf(iv[j], w23.x, acc[2][j]);
                    acc[3][j] = fmaf(iv[j], w23.y, acc[3][j]);
                }
            }
        }
    }

    float sst[4], sq[4];
#pragma unroll
    for (int c = 0; c < 4; ++c) { sst[c] = 0.f; sq[c] = 0.f; }
#pragma unroll
    for (int c = 0; c < 4; ++c) {
        float bv = bias[co0 + c];
#pragma unroll
        for (int j = 0; j < 6; ++j) {
            if (pv[j]) {
                int p = lane + j * 64;
                int r = p / 38, q = p - r * 38;
                float v = fmaxf(acc[c][j] + bv, 0.f);
                out[((n * 24 + co0 + c) * 38 + oh0 + r) * 38 + q] = v;
                sst[c] += v; sq[c] += v * v;
            }
        }
    }
#pragma unroll
    for (int o = 1; o < 64; o <<= 1) {
#pragma unroll
        for (int c = 0; c < 4; ++c) {
            sst[c] += __shfl_xor(sst[c], o);
            sq[c]  += __shfl_xor(sq[c], o);
        }
    }
    if (lane == 0) {
#pragma unroll
        for (int c = 0; c < 4; ++c) {
            red[(co0 + c) * 2]     = sst[c];
            red[(co0 + c) * 2 + 1] = sq[c];
        }
    }
    __syncthreads();
    if (tid < 48) atomicAdd(&statsOut[tid], (double)red[tid]);
}

// ============ conv2/3/4: CIN=24, staged in 24/CIB phases; COB co per block; NT threads ==
// r9-best strided staging. Round-13: conv2 instantiated with CIB=12 (LDS 39.7KB x 4
// blocks = 158.8KB, still 24 waves/CU) -> 2 staging phases instead of 3, one fewer
// barrier pair. ci summation order stays 0..23 ascending -> bit-identical accumulation;
// stats f64-atomic (replay-stable).
template <int HIN, int WIN, int HOUT, int WOUT, int OHT, int NP, int CIB, int COB, int NT>
__global__ __launch_bounds__(NT, 6) void conv24_bn(const float* __restrict__ in,
                                                   const float* __restrict__ wT,
                                                   const float* __restrict__ bias,
                                                   const double* __restrict__ statsIn,
                                                   const float* __restrict__ gIn,
                                                   const float* __restrict__ bIn, float invcntIn,
                                                   float* __restrict__ out,
                                                   double* __restrict__ statsOut, int tilesPerImg)
{
    constexpr int IR = 2 * OHT + 1;
    constexpr int ICW = 2 * WOUT + 1;
    constexpr int NPH = 24 / CIB;
    constexpr int NCO = 24 / COB;      // co-groups per image-tile
    constexpr int NW  = NT / 64;       // waves per block
    constexpr int CPW = COB / NW;      // co per wave (6/4/3/2)
    __shared__ float in_s[CIB * IR * ICW];
    __shared__ float aff[48];
    __shared__ float red[48];

    int bid = blockIdx.x;
    int n = bid / (tilesPerImg * NCO);
    int rem = bid - n * (tilesPerImg * NCO);
    int tile = rem / NCO;
    int coBase = (rem - tile * NCO) * COB;
    int oh0 = tile * OHT;
    int tid = threadIdx.x;

    if (tid < 24) {
        double meand = statsIn[tid * 2] * (double)invcntIn;
        double vard  = statsIn[tid * 2 + 1] * (double)invcntIn - meand * meand;
        float mean = (float)meand;
        float s    = gIn[tid] * rsqrtf((float)vard + 1e-5f);
        aff[tid * 2] = s;
        aff[tid * 2 + 1] = bIn[tid] - mean * s;
    }
    __syncthreads();

    int cg = tid >> 6, lane = tid & 63, co0 = coBase + cg * CPW;
    int nvr = HOUT - oh0; if (nvr > OHT) nvr = OHT;
    int nposv = nvr * WOUT;
    int off[NP];
    bool pv[NP];
#pragma unroll
    for (int j = 0; j < NP; ++j) {
        int p = lane + j * 64;
        pv[j] = p < nposv;
        int pc = pv[j] ? p : 0;
        int r0 = pc / WOUT, c0 = pc - r0 * WOUT;
        off[j] = (r0 * 2) * ICW + c0 * 2;
    }
    float acc[CPW][NP];
#pragma unroll
    for (int c = 0; c < CPW; ++c)
#pragma unroll
        for (int j = 0; j < NP; ++j) acc[c][j] = 0.f;

#pragma unroll 1
    for (int ph = 0; ph < NPH; ++ph) {
        if (ph) __syncthreads();   // all waves done reading previous phase's LDS
        for (int idx = tid; idx < CIB * IR * ICW; idx += NT) {
            int ci = idx / (IR * ICW);
            int rem2 = idx - ci * (IR * ICW);
            int r = rem2 / ICW, c = rem2 - r * ICW;
            int gci = ph * CIB + ci;
            int ih = 2 * oh0 - 1 + r, iw = c - 1;
            float v = 0.f;
            if ((unsigned)ih < (unsigned)HIN && (unsigned)iw < (unsigned)WIN)
                v = aff[gci * 2] * in[((n * 24 + gci) * HIN + ih) * WIN + iw] + aff[gci * 2 + 1];
            in_s[idx] = v;
        }
        __syncthreads();

#pragma unroll 1
        for (int ci = 0; ci < CIB; ++ci) {
            const float* ip = in_s + ci * (IR * ICW);
            const float* wp = wT + (ph * CIB + ci) * 9 * 24 + co0;
#pragma unroll
            for (int kh = 0; kh < 3; ++kh) {
#pragma unroll
                for (int kw = 0; kw < 3; ++kw) {
                    float iv[NP];
#pragma unroll
                    for (int j = 0; j < NP; ++j) iv[j] = ip[off[j] + kh * ICW + kw];
                    const float* wr = wp + (kh * 3 + kw) * 24;
                    if constexpr (CPW == 6) {
                        float2 w01 = *(const float2*)(wr);
                        float2 w23 = *(const float2*)(wr + 2);
                        float2 w45 = *(const float2*)(wr + 4);
#pragma unroll
                        for (int j = 0; j < NP; ++j) {
                            acc[0][j] = fmaf(iv[j], w01.x, acc[0][j]);
                            acc[1][j] = fmaf(iv[j], w01.y, acc[1][j]);
                            acc[2][j] = fmaf(iv[j], w23.x, acc[2][j]);
                            acc[3][j] = fmaf(iv[j], w23.y, acc[3][j]);
                            acc[4][j] = fmaf(iv[j], w45.x, acc[4][j]);
                            acc[5][j] = fmaf(iv[j], w45.y, acc[5][j]);
                        }
                    } else if constexpr (CPW == 4) {
                        float2 w01 = *(const float2*)(wr);
                        float2 w23 = *(const float2*)(wr + 2);
#pragma unroll
                        for (int j = 0; j < NP; ++j) {
                            acc[0][j] = fmaf(iv[j], w01.x, acc[0][j]);
                            acc[1][j] = fmaf(iv[j], w01.y, acc[1][j]);
                            acc[2][j] = fmaf(iv[j], w23.x, acc[2][j]);
                            acc[3][j] = fmaf(iv[j], w23.y, acc[3][j]);
                        }
                    } else if constexpr (CPW == 3) {
                        float w0 = wr[0], w1 = wr[1], w2 = wr[2];
#pragma unroll
                        for (int j = 0; j < NP; ++j) {
                            acc[0][j] = fmaf(iv[j], w0, acc[0][j]);
                            acc[1][j] = fmaf(iv[j], w1, acc[1][j]);
                            acc[2][j] = fmaf(iv[j], w2, acc[2][j]);
                        }
                    } else {   // CPW == 2
                        float2 w01 = *(const float2*)(wr);
#pragma unroll
                        for (int j = 0; j < NP; ++j) {
                            acc[0][j] = fmaf(iv[j], w01.x, acc[0][j]);
                            acc[1][j] = fmaf(iv[j], w01.y, acc[1][j]);
                        }
                    }
                }
            }
        }
    }

    float sst[CPW], sq[CPW];
#pragma unroll
    for (int c = 0; c < CPW; ++c) { sst[c] = 0.f; sq[c] = 0.f; }
#pragma unroll
    for (int c = 0; c < CPW; ++c) {
        float bv = bias[co0 + c];
#pragma unroll
        for (int j = 0; j < NP; ++j) {
            if (pv[j]) {
                int p = lane + j * 64;
                int r = p / WOUT, q = p - r * WOUT;
                float v = fmaxf(acc[c][j] + bv, 0.f);
                out[((n * 24 + co0 + c) * HOUT + oh0 + r) * WOUT + q] = v;
                sst[c] += v; sq[c] += v * v;
            }
        }
    }
#pragma unroll
    for (int o = 1; o < 64; o <<= 1) {
#pragma unroll
        for (int c = 0; c < CPW; ++c) {
            sst[c] += __shfl_xor(sst[c], o);
            sq[c]  += __shfl_xor(sq[c], o);
        }
    }
    if (lane == 0) {
#pragma unroll
        for (int c = 0; c < CPW; ++c) {
            int lc = cg * CPW + c;   // local channel within this block's COB
            red[lc * 2]     = sst[c];
            red[lc * 2 + 1] = sq[c];
        }
    }
    __syncthreads();
    if (tid < COB * 2) atomicAdd(&statsOut[coBase * 2 + tid], (double)red[tid]);
}

// ---------------- build bf16 features: xf26 = [BN4(conv4) 24ch, coords 2] ; qst bf16 ----------------
// Round-13: regrid — old version was 50 blocks (80% of the GPU idle) with a 24-channel
// serial loop per thread. Now one thread per item: qst [0,5632) | coords [5632,18432) |
// features (b,p,ch) [18432,325632) -> 1272 blocks. Same formulas, same values.
__global__ void build_features(const float* __restrict__ y4, const double* __restrict__ stats4,
                               const float* __restrict__ g4, const float* __restrict__ b4,
                               const float* __restrict__ qst,
                               bf16_t* __restrict__ xf26, bf16_t* __restrict__ qstb)
{
    int idx = blockIdx.x * 256 + threadIdx.x;
    if (idx < MB * 11) { qstb[idx] = (bf16_t)qst[idx]; return; }
    idx -= MB * 11;
    if (idx < MB * 25) {   // coords for row idx = b*25+p
        int p = idx % 25;
        xf26[idx * 26 + 24] = (bf16_t)((p / 5.0f - 2.0f) * 0.5f);
        xf26[idx * 26 + 25] = (bf16_t)(((float)(p % 5) - 2.0f) * 0.5f);
        return;
    }
    idx -= MB * 25;
    if (idx < MB * 25 * 24) {
        int ch = idx % 24, bp = idx / 24;
        int b = bp / 25, p = bp % 25;
        const double invcnt = 1.0 / (MB * 25);
        double meand = stats4[ch * 2] * invcnt;
        double vard  = stats4[ch * 2 + 1] * invcnt - meand * meand;
        float mean = (float)meand;
        float s    = g4[ch] * rsqrtf((float)vard + 1e-5f);
        float v    = s * y4[(b * 24 + ch) * 25 + p] + (b4[ch] - mean * s);
        xf26[bp * 26 + ch] = (bf16_t)v;
    }
}

// ------- weight prep: g-weights in MFMA-A-frag order, fp32 transposes for f-MLP, conv wT --------
// Wf layout per layer: [nt (N/32)][ks (K/16)][lane 0..63][j 0..7]
//   element = W[nt*32 + (lane&31)][ks*16 + (lane>>5)*8 + j]
__device__ __forceinline__ void frag256(int idx, const float* __restrict__ gw, bf16_t* __restrict__ Wf)
{
    int j = idx & 7, lane = (idx >> 3) & 63, ks = (idx >> 9) & 15, nt = idx >> 13;
    int n = nt * 32 + (lane & 31), k = ks * 16 + (lane >> 5) * 8 + j;
    Wf[idx] = (bf16_t)gw[n * 256 + k];
}

// total work items: 16384 + 3*65536 + 2*65536 + 648 + 3*5184 = 360,264 -> grid 1408x256 = 360,448
__global__ void prep_weights(const float* __restrict__ gw1, const float* __restrict__ gw2,
                             const float* __restrict__ gw3, const float* __restrict__ gw4,
                             const float* __restrict__ fw1, const float* __restrict__ fw2,
                             const float* __restrict__ c1w, const float* __restrict__ c2w,
                             const float* __restrict__ c3w, const float* __restrict__ c4w,
                             bf16_t* __restrict__ W1f, bf16_t* __restrict__ W2f,
                             bf16_t* __restrict__ W3f, bf16_t* __restrict__ W4f,
                             float* __restrict__ fw1T, float* __restrict__ fw2T,
                             float* __restrict__ wT1, float* __restrict__ wT2,
                             float* __restrict__ wT3, float* __restrict__ wT4)
{
    int idx = blockIdx.x * 256 + threadIdx.x;
    if (idx < 16384) {  // W1: K=64 (63 + zero pad), [8 nt][4 ks][64][8]
        int j = idx & 7, lane = (idx >> 3) & 63, ks = (idx >> 9) & 3, nt = idx >> 11;
        int n = nt * 32 + (lane & 31), k = ks * 16 + (lane >> 5) * 8 + j;
        W1f[idx] = (k < 63) ? (bf16_t)gw1[n * 63 + k] : (bf16_t)0.0f;
        return;
    }
    idx -= 16384;
    if (idx < 65536) { frag256(idx, gw2, W2f); return; }
    idx -= 65536;
    if (idx < 65536) { frag256(idx, gw3, W3f); return; }
    idx -= 65536;
    if (idx < 65536) { frag256(idx, gw4, W4f); return; }
    idx -= 65536;
    if (idx < 65536) { int k = idx >> 8, nn = idx & 255; fw1T[idx] = fw1[nn * 256 + k]; return; }
    idx -= 65536;
    if (idx < 65536) { int k = idx >> 8, nn = idx & 255; fw2T[idx] = fw2[nn * 256 + k]; return; }
    idx -= 65536;
    if (idx < 648)   { int k = idx / 24, co = idx - k * 24; wT1[idx] = c1w[co * 27 + k]; return; }
    idx -= 648;
    if (idx < 5184)  { int k = idx / 24, co = idx - k * 24; wT2[idx] = c2w[co * 216 + k]; return; }
    idx -= 5184;
    if (idx < 5184)  { int k = idx / 24, co = idx - k * 24; wT3[idx] = c3w[co * 216 + k]; return; }
    idx -= 5184;
    if (idx < 5184)  { int k = idx / 24, co = idx - k * 24; wT4[idx] = c4w[co * 216 + k]; return; }
}

// ---------------- fused g-MLP: 32x32x16 MFMA, swapped operands (A=W, B=h^T), swizzled LDS ----------------
// r9-best body, untouched (no setprio — r8 regression; no hf-dbuf — r10 null). Pinned at
// ~151us / MfmaUtil 40% across 7 variants; the multi-pipe floor (MFMA 56 + LDS ~35 + L2-W
// 31 + VALU ~42, poorly overlapped at 2 waves/SIMD) needs wave-specialization asm to break.

template <int NKS>
__device__ __forceinline__ void g_quarter(const bf16_t* hs, const bf16_t* __restrict__ wbase0,
                                          const bf16_t* __restrict__ wbase1,
                                          int q, int m31, int half,
                                          bf16x8 (&CUR)[2][4], bf16x8 (&NXT)[2][4],
                                          f32x16 (&acc)[4][2])
{
    if (q + 1 < NKS / 4) {   // prefetch next quarter's wf while this quarter's MFMAs run
#pragma unroll
        for (int k = 0; k < 4; ++k) {
            NXT[0][k] = *(const bf16x8*)(wbase0 + (size_t)((q + 1) * 4 + k) * 512);
            NXT[1][k] = *(const bf16x8*)(wbase1 + (size_t)((q + 1) * 4 + k) * 512);
        }
    }
#pragma unroll
    for (int kk = 0; kk < 4; ++kk) {
        int ks = q * 4 + kk;
        int kc = ks * 2 + half;
        bf16x8 hf[4];
#pragma unroll
        for (int mt = 0; mt < 4; ++mt) {
            int m = mt * 32 + m31;
            hf[mt] = *(const bf16x8*)(hs + m * 256 + ((kc ^ m31) << 3));
        }
#pragma unroll
        for (int mt = 0; mt < 4; ++mt) {
            acc[mt][0] = __builtin_amdgcn_mfma_f32_32x32x16_bf16(CUR[0][kk], hf[mt], acc[mt][0], 0, 0, 0);
            acc[mt][1] = __builtin_amdgcn_mfma_f32_32x32x16_bf16(CUR[1][kk], hf[mt], acc[mt][1], 0, 0, 0);
        }
    }
}

template <int NKS>  // K/16: 4 for layer1, 16 for layers 2-4
__device__ __forceinline__ void g_layer(const bf16_t* hs, const bf16_t* __restrict__ Wf,
                                        int wid, int lane, f32x16 (&acc)[4][2])
{
    int m31 = lane & 31, half = lane >> 5;
#pragma unroll
    for (int mt = 0; mt < 4; ++mt)
#pragma unroll
        for (int nt = 0; nt < 2; ++nt) acc[mt][nt] = (f32x16)(0.f);

    const bf16_t* wbase0 = Wf + (size_t)(((wid * 2 + 0) * NKS) * 64 + lane) * 8;
    const bf16_t* wbase1 = Wf + (size_t)(((wid * 2 + 1) * NKS) * 64 + lane) * 8;
    bf16x8 wA[2][4], wB[2][4];
#pragma unroll
    for (int k = 0; k < 4; ++k) {   // preload quarter 0
        wA[0][k] = *(const bf16x8*)(wbase0 + (size_t)k * 512);
        wA[1][k] = *(const bf16x8*)(wbase1 + (size_t)k * 512);
    }
#pragma unroll
    for (int q = 0; q < NKS / 4; ++q) {
        if ((q & 1) == 0) g_quarter<NKS>(hs, wbase0, wbase1, q, m31, half, wA, wB, acc);
        else              g_quarter<NKS>(hs, wbase0, wbase1, q, m31, half, wB, wA, acc);
    }
}

__device__ __forceinline__ void g_store(bf16_t* hs, const float* __restrict__ bias,
                                        int wid, int lane, f32x16 (&acc)[4][2])
{
    int m31 = lane & 31, half = lane >> 5;
#pragma unroll
    for (int mt = 0; mt < 4; ++mt) {
        int m = mt * 32 + m31;
#pragma unroll
        for (int nt = 0; nt < 2; ++nt) {
            int nbase = (wid * 2 + nt) * 32;
#pragma unroll
            for (int g = 0; g < 4; ++g) {
                int n0 = nbase + g * 8 + half * 4;
                float4 bv = *(const float4*)(bias + n0);
                bf16x4 v;
                v[0] = (bf16_t)fmaxf(acc[mt][nt][g * 4 + 0] + bv.x, 0.f);
                v[1] = (bf16_t)fmaxf(acc[mt][nt][g * 4 + 1] + bv.y, 0.f);
                v[2] = (bf16_t)fmaxf(acc[mt][nt][g * 4 + 2] + bv.z, 0.f);
                v[3] = (bf16_t)fmaxf(acc[mt][nt][g * 4 + 3] + bv.w, 0.f);
                int chunk = n0 >> 3;  // half*4 < 8, so chunk = (nbase + g*8) >> 3
                *(bf16x4*)(hs + m * 256 + ((chunk ^ m31) << 3) + (half << 2)) = v;
            }
        }
    }
}

__global__ void __launch_bounds__(256, 2)
g_mlp(const bf16_t* __restrict__ xf26, const bf16_t* __restrict__ qstb,
      const bf16_t* __restrict__ W1f, const bf16_t* __restrict__ W2f,
      const bf16_t* __restrict__ W3f, const bf16_t* __restrict__ W4f,
      const float* __restrict__ b1, const float* __restrict__ b2,
      const float* __restrict__ b3, const float* __restrict__ b4,
      float* __restrict__ xg5)
{
    __shared__ __align__(16) bf16_t hs[GROWS * 256];   // 65,536 B
    int b    = blockIdx.x / GT_PER_B;
    int tile = blockIdx.x % GT_PER_B;
    int tid  = threadIdx.x;

    // stage features (64 bf16 per row -> chunks 0..7, swizzled)
    for (int i = tid; i < GROWS * 8; i += 256) {
        int m = i >> 3, c = i & 7;
        int p = tile * GROWS + m;
        bf16x8 v;
        if (p < 625) {
            int a = p / 25, cp = p - a * 25;
            const bf16_t* f1 = xf26 + (b * 25 + cp) * 26;
            const bf16_t* f2 = xf26 + (b * 25 + a) * 26;
            const bf16_t* f3 = qstb + b * 11;
#pragma unroll
            for (int j = 0; j < 8; ++j) {
                int col = c * 8 + j;
                bf16_t u = (bf16_t)0.0f;
                if (col < 26) u = f1[col];
                else if (col < 52) u = f2[col - 26];
                else if (col < 63) u = f3[col - 52];
                v[j] = u;
            }
        } else {
#pragma unroll
            for (int j = 0; j < 8; ++j) v[j] = (bf16_t)0.0f;
        }
        *(bf16x8*)(hs + m * 256 + ((c ^ (m & 31)) << 3)) = v;
    }
    __syncthreads();

    int wid = tid >> 6, lane = tid & 63;
    int m31 = lane & 31, half = lane >> 5;
    f32x16 acc[4][2];

    g_layer<4>(hs, W1f, wid, lane, acc);
    __syncthreads(); g_store(hs, b1, wid, lane, acc); __syncthreads();
    g_layer<16>(hs, W2f, wid, lane, acc);
    __syncthreads(); g_store(hs, b2, wid, lane, acc); __syncthreads();
    g_layer<16>(hs, W3f, wid, lane, acc);
    __syncthreads(); g_store(hs, b3, wid, lane, acc); __syncthreads();
    g_layer<16>(hs, W4f, wid, lane, acc);

    // epilogue: relu(acc + b4), mask invalid rows, sum over m, plain store into xg5 slot
#pragma unroll
    for (int nt = 0; nt < 2; ++nt) {
        int nbase = (wid * 2 + nt) * 32;
        float bf[16];
#pragma unroll
        for (int r = 0; r < 16; ++r)
            bf[r] = b4[nbase + (r & 3) + 8 * (r >> 2) + 4 * half];
        f32x16 t = (f32x16)(0.f);
#pragma unroll
        for (int mt = 0; mt < 4; ++mt) {
            int p = tile * GROWS + mt * 32 + m31;
            if (p < 625) {
#pragma unroll
                for (int r = 0; r < 16; ++r)
                    t[r] += fmaxf(acc[mt][nt][r] + bf[r], 0.f);
            }
        }
#pragma unroll
        for (int off = 1; off < 32; off <<= 1) {
#pragma unroll
            for (int r = 0; r < 16; ++r) t[r] += __shfl_xor(t[r], off);
        }
        if (m31 == 0) {
#pragma unroll
            for (int r = 0; r < 16; ++r) {
                int nn = nbase + (r & 3) + 8 * (r >> 2) + 4 * half;
                xg5[(b * GT_PER_B + tile) * 256 + nn] = t[r];
            }
        }
    }
}

// ---------------- f-MLP (fp32) + log_softmax ----------------
// Round-13: k-split over 2 halves — old 256-thr version was grid-limited to 8 waves/CU
// with 256-deep serial k-loops (latency-bound). 512 threads: thread (t,h) sums
// k in [h*128,(h+1)*128); LDS combine adds the halves + bias. 16 waves/CU, half-depth
// loops. fp32 sum order changes only at the half boundary (deterministic).
__global__ __launch_bounds__(512) void f_mlp(const float* __restrict__ xg5,
                      const float* __restrict__ fw1T, const float* __restrict__ fb1,
                      const float* __restrict__ fw2T, const float* __restrict__ fb2,
                      const float* __restrict__ fw3, const float* __restrict__ fb3,
                      float* __restrict__ out)
{
    __shared__ float xa[256], xb[256], part[512];
    int b = blockIdx.x;
    int t = threadIdx.x & 255, h = threadIdx.x >> 8;   // h in {0,1}
    if (h == 0) {
        float s0 = 0.f;
#pragma unroll
        for (int i = 0; i < GT_PER_B; ++i) s0 += xg5[(b * GT_PER_B + i) * 256 + t];
        xa[t] = s0;
    }
    __syncthreads();
    // layer 1
    {
        float a = 0.f;
        const float* w = fw1T + (h * 128) * 256 + t;
        for (int k = 0; k < 128; ++k) a += w[k * 256] * xa[h * 128 + k];
        part[h * 256 + t] = a;
    }
    __syncthreads();
    if (h == 0) xb[t] = fmaxf(part[t] + part[256 + t] + fb1[t], 0.f);
    __syncthreads();
    // layer 2
    {
        float a = 0.f;
        const float* w = fw2T + (h * 128) * 256 + t;
        for (int k = 0; k < 128; ++k) a += w[k * 256] * xb[h * 128 + k];
        part[h * 256 + t] = a;
    }
    __syncthreads();
    if (h == 0) xa[t] = fmaxf(part[t] + part[256 + t] + fb2[t], 0.f);
    __syncthreads();
    // layer 3 (10 outputs): 20 threads, (o, hh) halves
    if (threadIdx.x < 20) {
        int o = threadIdx.x % 10, hh = threadIdx.x / 10;
        float s = 0.f;
        for (int k = hh * 128; k < hh * 128 + 128; ++k) s += fw3[o * 256 + k] * xa[k];
        part[hh * 10 + o] = s;
    }
    __syncthreads();
    if (threadIdx.x == 0) {
        float lg[10];
#pragma unroll
        for (int i = 0; i < 10; ++i) lg[i] = part[i] + part[10 + i] + fb3[i];
        float m = lg[0];
        for (int i = 1; i < 10; ++i) m = fmaxf(m, lg[i]);
        float s = 0.f;
        for (int i = 0; i < 10; ++i) s += expf(lg[i] - m);
        float ls = m + logf(s);
        for (int i = 0; i < 10; ++i) out[b * 10 + i] = lg[i] - ls;
    }
}

// ---------------- launch ----------------
extern "C" void kernel_launch(void* const* d_in, const int* in_sizes, int n_in,
                              void* d_out, int out_size, void* d_ws, size_t ws_size,
                              hipStream_t stream)
{
    (void)in_sizes; (void)n_in; (void)out_size; (void)ws_size;
    const float* img  = (const float*)d_in[0];
    const float* qst  = (const float*)d_in[1];
    const float* c1w  = (const float*)d_in[2];
    const float* c1b  = (const float*)d_in[3];
    const float* bn1g = (const float*)d_in[4];
    const float* bn1b = (const float*)d_in[5];
    const float* c2w  = (const float*)d_in[6];
    const float* c2b  = (const float*)d_in[7];
    const float* bn2g = (const float*)d_in[8];
    const float* bn2b = (const float*)d_in[9];
    const float* c3w  = (const float*)d_in[10];
    const float* c3b  = (const float*)d_in[11];
    const float* bn3g = (const float*)d_in[12];
    const float* bn3b = (const float*)d_in[13];
    const float* c4w  = (const float*)d_in[14];
    const float* c4b  = (const float*)d_in[15];
    const float* bn4g = (const float*)d_in[16];
    const float* bn4b = (const float*)d_in[17];
    const float* gw1  = (const float*)d_in[18];
    const float* gb1  = (const float*)d_in[19];
    const float* gw2  = (const float*)d_in[20];
    const float* gb2  = (const float*)d_in[21];
    const float* gw3  = (const float*)d_in[22];
    const float* gb3  = (const float*)d_in[23];
    const float* gw4  = (const float*)d_in[24];
    const float* gb4  = (const float*)d_in[25];
    const float* fw1  = (const float*)d_in[26];
    const float* fb1  = (const float*)d_in[27];
    const float* fw2  = (const float*)d_in[28];
    const float* fb2  = (const float*)d_in[29];
    const float* fw3  = (const float*)d_in[30];
    const float* fb3  = (const float*)d_in[31];

    const int Y1 = 512 * 24 * 38 * 38;
    const int Y2 = 512 * 24 * 19 * 19;
    const int Y3 = 512 * 24 * 10 * 10;
    const int Y4 = 512 * 24 * 5 * 5;

    // stats in DOUBLE at the head of ws (8B-aligned); everything else after
    double* stats = (double*)d_ws;       // [4 layers][24 ch][sum, sumsq] = 192 doubles
    float* fp = (float*)(stats + 192);
    float* y1    = fp;  fp += Y1;
    float* y2    = fp;  fp += Y2;
    float* y3    = fp;  fp += Y3;
    float* y4    = fp;  fp += Y4;
    float* xg5   = fp;  fp += 512 * GT_PER_B * 256;   // per-tile partial sums (no atomics)
    float* fw1T  = fp;  fp += 65536;
    float* fw2T  = fp;  fp += 65536;
    float* wT1   = fp;  fp += 648;       // conv weights transposed [k][24]
    float* wT2   = fp;  fp += 5184;
    float* wT3   = fp;  fp += 5184;
    float* wT4   = fp;  fp += 5184;
    bf16_t* bp   = (bf16_t*)fp;
    bf16_t* xf26 = bp;  bp += 512 * 25 * 26;
    bf16_t* qstb = bp;  bp += 512 * 11;
    bf16_t* W1f  = bp;  bp += 16384;     // g-weights in MFMA frag order
    bf16_t* W2f  = bp;  bp += 65536;
    bf16_t* W3f  = bp;  bp += 65536;
    bf16_t* W4f  = bp;  bp += 65536;

    hipMemsetAsync(stats, 0, 192 * sizeof(double), stream);

    // grid MUST cover all 360,264 work items (ceil -> 1408 blocks)
    prep_weights<<<1408, 256, 0, stream>>>(gw1, gw2, gw3, gw4, fw1, fw2, c1w, c2w, c3w, c4w,
                                           W1f, W2f, W3f, W4f, fw1T, fw2T,
                                           wT1, wT2, wT3, wT4);

    // conv1: 4 row-tiles of 10 per image, 384-thread blocks (6 waves x 4 co)
    conv1_bn<<<2048, 384, 0, stream>>>(img, wT1, c1b, y1, stats + 0);

    // conv2: 2 row-tiles of 10, CIB=12 (2 staging phases, LDS 39.7KB, still 24 waves/CU)
    conv24_bn<38, 38, 19, 19, 10, 3, 12, 24, 384><<<1024, 384, 0, stream>>>(
        y1, wT2, c2b, stats + 0, bn1g, bn1b, 1.f / (512.f * 1444.f),
        y2, stats + 48, 2);

    // conv3: co-split (12 co per block), 384thr (CPW=2) -> 24 waves/CU
    conv24_bn<19, 19, 10, 10, 10, 2, 12, 12, 384><<<1024, 384, 0, stream>>>(
        y2, wT3, c3b, stats + 48, bn2g, bn2b, 1.f / (512.f * 361.f),
        y3, stats + 96, 1);

    // conv4: co-split (12 co per block), 384thr (CPW=2)
    conv24_bn<10, 10, 5, 5, 5, 1, 12, 12, 384><<<1024, 384, 0, stream>>>(
        y3, wT4, c4b, stats + 96, bn3g, bn3b, 1.f / (512.f * 100.f),
        y4, stats + 144, 1);

    // build_features: one thread per item (qst 5632 + coords 12800 + features 307200
    // = 325,632 items -> 1272 blocks; was 50 blocks with a serial 24-ch loop)
    build_features<<<1272, 256, 0, stream>>>(y4, stats + 144, bn4g, bn4b, qst, xf26, qstb);

    g_mlp<<<512 * GT_PER_B, 256, 0, stream>>>(xf26, qstb, W1f, W2f, W3f, W4f,
                                              gb1, gb2, gb3, gb4, xg5);

    // f_mlp: 512 threads (k-split halves) -> 16 waves/CU
    f_mlp<<<512, 512, 0, stream>>>(xg5, fw1T, fb1, fw2T, fb2, fw3, fb3, (float*)d_out);
}

// Round 14
// 520.256 us; speedup vs baseline: 1.0516x; 1.0052x over previous
//
#include <hip/hip_runtime.h>

typedef __bf16 bf16_t;
typedef __bf16 bf16x8 __attribute__((ext_vector_type(8)));
typedef __bf16 bf16x4 __attribute__((ext_vector_type(4)));
typedef float f32x16 __attribute__((ext_vector_type(16)));

#define MB 512
#define GROWS 128     // pair rows per g-block (4 mtiles of 32)
#define GT_PER_B 5    // ceil(625/128)

// ================= conv1: CIN=3, 75x75 -> 38x38 ============
// Round-14: LDS row stride padded 77->78 (even dwords -> 8B-aligned taps) and kw-hoisted
// tap loads: per (j,kh) one ds_read_b64 (kw 0,1) + one b32 (kw 2) instead of 3 scalar
// reads — conv LDS-issue is the per-CU binding pipe (~5.8cyc/read). FMA order per
// accumulator unchanged (ci,kh,kw ascending) -> bit-identical. 384 thr, strided staging
// (r10/r11 showed row-loop staging costs 12us of MLP). Stats in f64 atomics.
__global__ __launch_bounds__(384, 6) void conv1_bn(const float* __restrict__ img,
                                                   const float* __restrict__ wT,
                                                   const float* __restrict__ bias,
                                                   float* __restrict__ out,
                                                   double* __restrict__ statsOut)
{
    constexpr int ICWP = 78;              // padded row stride (77 data cols + 1 pad)
    __shared__ float in_s[3 * 21 * ICWP]; // 19,656 B
    __shared__ float red[48];
    int bid = blockIdx.x;
    int n = bid >> 2, tile = bid & 3;
    int oh0 = tile * 10;
    int tid = threadIdx.x;

    for (int idx = tid; idx < 3 * 21 * 77; idx += 384) {
        int ci = idx / (21 * 77);
        int rem = idx - ci * (21 * 77);
        int r = rem / 77, c = rem - r * 77;
        int ih = 2 * oh0 - 1 + r, iw = c - 1;
        float v = 0.f;
        if ((unsigned)ih < 75u && (unsigned)iw < 75u)
            v = img[((n * 3 + ci) * 75 + ih) * 75 + iw];
        in_s[(ci * 21 + r) * ICWP + c] = v;
    }
    __syncthreads();

    int cg = tid >> 6, lane = tid & 63, co0 = cg * 4;   // 6 waves x 4 co
    int nvr = 38 - oh0; if (nvr > 10) nvr = 10;
    int nposv = nvr * 38;
    int off[6];
    bool pv[6];
#pragma unroll
    for (int j = 0; j < 6; ++j) {
        int p = lane + j * 64;
        pv[j] = p < nposv;
        int pc = pv[j] ? p : 0;
        int r0 = pc / 38, c0 = pc - r0 * 38;
        off[j] = (r0 * 2) * ICWP + c0 * 2;   // even -> 8B aligned
    }
    float acc[4][6];
#pragma unroll
    for (int c = 0; c < 4; ++c)
#pragma unroll
        for (int j = 0; j < 6; ++j) acc[c][j] = 0.f;

#pragma unroll 1
    for (int ci = 0; ci < 3; ++ci) {
        const float* ip = in_s + ci * (21 * ICWP);
        const float* wp = wT + ci * 9 * 24 + co0;
#pragma unroll
        for (int kh = 0; kh < 3; ++kh) {
            float iv[6][3];
#pragma unroll
            for (int j = 0; j < 6; ++j) {
                const float* p = ip + off[j] + kh * ICWP;   // even dword -> b64 ok
                float2 v01 = *(const float2*)(p);
                iv[j][0] = v01.x; iv[j][1] = v01.y; iv[j][2] = p[2];
            }
#pragma unroll
            for (int kw = 0; kw < 3; ++kw) {
                const float* wr = wp + (kh * 3 + kw) * 24;
                float2 w01 = *(const float2*)(wr);
                float2 w23 = *(const float2*)(wr + 2);
#pragma unroll
                for (int j = 0; j < 6; ++j) {
                    acc[0][j] = fmaf(iv[j][kw], w01.x, acc[0][j]);
                    acc[1][j] = fmaf(iv[j][kw], w01.y, acc[1][j]);
                    acc[2][j] = fmaf(iv[j][kw], w23.x, acc[2][j]);
                    acc[3][j] = fmaf(iv[j][kw], w23.y, acc[3][j]);
                }
            }
        }
    }

    float sst[4], sq[4];
#pragma unroll
    for (int c = 0; c < 4; ++c) { sst[c] = 0.f; sq[c] = 0.f; }
#pragma unroll
    for (int c = 0; c < 4; ++c) {
        float bv = bias[co0 + c];
#pragma unroll
        for (int j = 0; j < 6; ++j) {
            if (pv[j]) {
                int p = lane + j * 64;
                int r = p / 38, q = p - r * 38;
                float v = fmaxf(acc[c][j] + bv, 0.f);
                out[((n * 24 + co0 + c) * 38 + oh0 + r) * 38 + q] = v;
                sst[c] += v; sq[c] += v * v;
            }
        }
    }
#pragma unroll
    for (int o = 1; o < 64; o <<= 1) {
#pragma unroll
        for (int c = 0; c < 4; ++c) {
            sst[c] += __shfl_xor(sst[c], o);
            sq[c]  += __shfl_xor(sq[c], o);
        }
    }
    if (lane == 0) {
#pragma unroll
        for (int c = 0; c < 4; ++c) {
            red[(co0 + c) * 2]     = sst[c];
            red[(co0 + c) * 2 + 1] = sq[c];
        }
    }
    __syncthreads();
    if (tid < 48) atomicAdd(&statsOut[tid], (double)red[tid]);
}

// ============ conv2/3/4: CIN=24, staged in 24/CIB phases; COB co per block; NT threads ==
// Round-14: padded LDS stride (ICWP = ICW+1, even) + kw-hoisted b64/b32 tap loads
// (2 LDS instr per 3 taps, was 3). conv2 LDS: 12x21x40x4 = 40,320B; 4 resident blocks
// = 162.8KB <= 160KiB pool. FMA order (ci,kh,kw) unchanged -> bit-identical; staging
// values unchanged (padded stride only). Stats f64-atomic (replay-stable).
template <int HIN, int WIN, int HOUT, int WOUT, int OHT, int NP, int CIB, int COB, int NT>
__global__ __launch_bounds__(NT, 6) void conv24_bn(const float* __restrict__ in,
                                                   const float* __restrict__ wT,
                                                   const float* __restrict__ bias,
                                                   const double* __restrict__ statsIn,
                                                   const float* __restrict__ gIn,
                                                   const float* __restrict__ bIn, float invcntIn,
                                                   float* __restrict__ out,
                                                   double* __restrict__ statsOut, int tilesPerImg)
{
    constexpr int IR = 2 * OHT + 1;
    constexpr int ICW = 2 * WOUT + 1;
    constexpr int ICWP = ICW + 1;      // even padded stride -> 8B-aligned taps
    constexpr int NPH = 24 / CIB;
    constexpr int NCO = 24 / COB;      // co-groups per image-tile
    constexpr int NW  = NT / 64;       // waves per block
    constexpr int CPW = COB / NW;      // co per wave (6/4/3/2)
    __shared__ float in_s[CIB * IR * ICWP];
    __shared__ float aff[48];
    __shared__ float red[48];

    int bid = blockIdx.x;
    int n = bid / (tilesPerImg * NCO);
    int rem = bid - n * (tilesPerImg * NCO);
    int tile = rem / NCO;
    int coBase = (rem - tile * NCO) * COB;
    int oh0 = tile * OHT;
    int tid = threadIdx.x;

    if (tid < 24) {
        double meand = statsIn[tid * 2] * (double)invcntIn;
        double vard  = statsIn[tid * 2 + 1] * (double)invcntIn - meand * meand;
        float mean = (float)meand;
        float s    = gIn[tid] * rsqrtf((float)vard + 1e-5f);
        aff[tid * 2] = s;
        aff[tid * 2 + 1] = bIn[tid] - mean * s;
    }
    __syncthreads();

    int cg = tid >> 6, lane = tid & 63, co0 = coBase + cg * CPW;
    int nvr = HOUT - oh0; if (nvr > OHT) nvr = OHT;
    int nposv = nvr * WOUT;
    int off[NP];
    bool pv[NP];
#pragma unroll
    for (int j = 0; j < NP; ++j) {
        int p = lane + j * 64;
        pv[j] = p < nposv;
        int pc = pv[j] ? p : 0;
        int r0 = pc / WOUT, c0 = pc - r0 * WOUT;
        off[j] = (r0 * 2) * ICWP + c0 * 2;   // even -> 8B aligned
    }
    float acc[CPW][NP];
#pragma unroll
    for (int c = 0; c < CPW; ++c)
#pragma unroll
        for (int j = 0; j < NP; ++j) acc[c][j] = 0.f;

#pragma unroll 1
    for (int ph = 0; ph < NPH; ++ph) {
        if (ph) __syncthreads();   // all waves done reading previous phase's LDS
        for (int idx = tid; idx < CIB * IR * ICW; idx += NT) {
            int ci = idx / (IR * ICW);
            int rem2 = idx - ci * (IR * ICW);
            int r = rem2 / ICW, c = rem2 - r * ICW;
            int gci = ph * CIB + ci;
            int ih = 2 * oh0 - 1 + r, iw = c - 1;
            float v = 0.f;
            if ((unsigned)ih < (unsigned)HIN && (unsigned)iw < (unsigned)WIN)
                v = aff[gci * 2] * in[((n * 24 + gci) * HIN + ih) * WIN + iw] + aff[gci * 2 + 1];
            in_s[(ci * IR + r) * ICWP + c] = v;
        }
        __syncthreads();

#pragma unroll 1
        for (int ci = 0; ci < CIB; ++ci) {
            const float* ip = in_s + ci * (IR * ICWP);
            const float* wp = wT + (ph * CIB + ci) * 9 * 24 + co0;
#pragma unroll
            for (int kh = 0; kh < 3; ++kh) {
                float iv[NP][3];
#pragma unroll
                for (int j = 0; j < NP; ++j) {
                    const float* p = ip + off[j] + kh * ICWP;
                    float2 v01 = *(const float2*)(p);
                    iv[j][0] = v01.x; iv[j][1] = v01.y; iv[j][2] = p[2];
                }
#pragma unroll
                for (int kw = 0; kw < 3; ++kw) {
                    const float* wr = wp + (kh * 3 + kw) * 24;
                    if constexpr (CPW == 6) {
                        float2 w01 = *(const float2*)(wr);
                        float2 w23 = *(const float2*)(wr + 2);
                        float2 w45 = *(const float2*)(wr + 4);
#pragma unroll
                        for (int j = 0; j < NP; ++j) {
                            acc[0][j] = fmaf(iv[j][kw], w01.x, acc[0][j]);
                            acc[1][j] = fmaf(iv[j][kw], w01.y, acc[1][j]);
                            acc[2][j] = fmaf(iv[j][kw], w23.x, acc[2][j]);
                            acc[3][j] = fmaf(iv[j][kw], w23.y, acc[3][j]);
                            acc[4][j] = fmaf(iv[j][kw], w45.x, acc[4][j]);
                            acc[5][j] = fmaf(iv[j][kw], w45.y, acc[5][j]);
                        }
                    } else if constexpr (CPW == 4) {
                        float2 w01 = *(const float2*)(wr);
                        float2 w23 = *(const float2*)(wr + 2);
#pragma unroll
                        for (int j = 0; j < NP; ++j) {
                            acc[0][j] = fmaf(iv[j][kw], w01.x, acc[0][j]);
                            acc[1][j] = fmaf(iv[j][kw], w01.y, acc[1][j]);
                            acc[2][j] = fmaf(iv[j][kw], w23.x, acc[2][j]);
                            acc[3][j] = fmaf(iv[j][kw], w23.y, acc[3][j]);
                        }
                    } else if constexpr (CPW == 3) {
                        float w0 = wr[0], w1 = wr[1], w2 = wr[2];
#pragma unroll
                        for (int j = 0; j < NP; ++j) {
                            acc[0][j] = fmaf(iv[j][kw], w0, acc[0][j]);
                            acc[1][j] = fmaf(iv[j][kw], w1, acc[1][j]);
                            acc[2][j] = fmaf(iv[j][kw], w2, acc[2][j]);
                        }
                    } else {   // CPW == 2
                        float2 w01 = *(const float2*)(wr);
#pragma unroll
                        for (int j = 0; j < NP; ++j) {
                            acc[0][j] = fmaf(iv[j][kw], w01.x, acc[0][j]);
                            acc[1][j] = fmaf(iv[j][kw], w01.y, acc[1][j]);
                        }
                    }
                }
            }
        }
    }

    float sst[CPW], sq[CPW];
#pragma unroll
    for (int c = 0; c < CPW; ++c) { sst[c] = 0.f; sq[c] = 0.f; }
#pragma unroll
    for (int c = 0; c < CPW; ++c) {
        float bv = bias[co0 + c];
#pragma unroll
        for (int j = 0; j < NP; ++j) {
            if (pv[j]) {
                int p = lane + j * 64;
                int r = p / WOUT, q = p - r * WOUT;
                float v = fmaxf(acc[c][j] + bv, 0.f);
                out[((n * 24 + co0 + c) * HOUT + oh0 + r) * WOUT + q] = v;
                sst[c] += v; sq[c] += v * v;
            }
        }
    }
#pragma unroll
    for (int o = 1; o < 64; o <<= 1) {
#pragma unroll
        for (int c = 0; c < CPW; ++c) {
            sst[c] += __shfl_xor(sst[c], o);
            sq[c]  += __shfl_xor(sq[c], o);
        }
    }
    if (lane == 0) {
#pragma unroll
        for (int c = 0; c < CPW; ++c) {
            int lc = cg * CPW + c;   // local channel within this block's COB
            red[lc * 2]     = sst[c];
            red[lc * 2 + 1] = sq[c];
        }
    }
    __syncthreads();
    if (tid < COB * 2) atomicAdd(&statsOut[coBase * 2 + tid], (double)red[tid]);
}

// ---------------- build bf16 features: xf26 = [BN4(conv4) 24ch, coords 2] ; qst bf16 ----------------
// One thread per item: qst | coords | features (b,p,ch) -> 1272 blocks (r13 regrid).
__global__ void build_features(const float* __restrict__ y4, const double* __restrict__ stats4,
                               const float* __restrict__ g4, const float* __restrict__ b4,
                               const float* __restrict__ qst,
                               bf16_t* __restrict__ xf26, bf16_t* __restrict__ qstb)
{
    int idx = blockIdx.x * 256 + threadIdx.x;
    if (idx < MB * 11) { qstb[idx] = (bf16_t)qst[idx]; return; }
    idx -= MB * 11;
    if (idx < MB * 25) {   // coords for row idx = b*25+p
        int p = idx % 25;
        xf26[idx * 26 + 24] = (bf16_t)((p / 5.0f - 2.0f) * 0.5f);
        xf26[idx * 26 + 25] = (bf16_t)(((float)(p % 5) - 2.0f) * 0.5f);
        return;
    }
    idx -= MB * 25;
    if (idx < MB * 25 * 24) {
        int ch = idx % 24, bp = idx / 24;
        int b = bp / 25, p = bp % 25;
        const double invcnt = 1.0 / (MB * 25);
        double meand = stats4[ch * 2] * invcnt;
        double vard  = stats4[ch * 2 + 1] * invcnt - meand * meand;
        float mean = (float)meand;
        float s    = g4[ch] * rsqrtf((float)vard + 1e-5f);
        float v    = s * y4[(b * 24 + ch) * 25 + p] + (b4[ch] - mean * s);
        xf26[bp * 26 + ch] = (bf16_t)v;
    }
}

// ------- weight prep: g-weights in MFMA-A-frag order, fp32 transposes for f-MLP, conv wT --------
// Wf layout per layer: [nt (N/32)][ks (K/16)][lane 0..63][j 0..7]
//   element = W[nt*32 + (lane&31)][ks*16 + (lane>>5)*8 + j]
__device__ __forceinline__ void frag256(int idx, const float* __restrict__ gw, bf16_t* __restrict__ Wf)
{
    int j = idx & 7, lane = (idx >> 3) & 63, ks = (idx >> 9) & 15, nt = idx >> 13;
    int n = nt * 32 + (lane & 31), k = ks * 16 + (lane >> 5) * 8 + j;
    Wf[idx] = (bf16_t)gw[n * 256 + k];
}

// total work items: 16384 + 3*65536 + 2*65536 + 648 + 3*5184 = 360,264 -> grid 1408x256 = 360,448
__global__ void prep_weights(const float* __restrict__ gw1, const float* __restrict__ gw2,
                             const float* __restrict__ gw3, const float* __restrict__ gw4,
                             const float* __restrict__ fw1, const float* __restrict__ fw2,
                             const float* __restrict__ c1w, const float* __restrict__ c2w,
                             const float* __restrict__ c3w, const float* __restrict__ c4w,
                             bf16_t* __restrict__ W1f, bf16_t* __restrict__ W2f,
                             bf16_t* __restrict__ W3f, bf16_t* __restrict__ W4f,
                             float* __restrict__ fw1T, float* __restrict__ fw2T,
                             float* __restrict__ wT1, float* __restrict__ wT2,
                             float* __restrict__ wT3, float* __restrict__ wT4)
{
    int idx = blockIdx.x * 256 + threadIdx.x;
    if (idx < 16384) {  // W1: K=64 (63 + zero pad), [8 nt][4 ks][64][8]
        int j = idx & 7, lane = (idx >> 3) & 63, ks = (idx >> 9) & 3, nt = idx >> 11;
        int n = nt * 32 + (lane & 31), k = ks * 16 + (lane >> 5) * 8 + j;
        W1f[idx] = (k < 63) ? (bf16_t)gw1[n * 63 + k] : (bf16_t)0.0f;
        return;
    }
    idx -= 16384;
    if (idx < 65536) { frag256(idx, gw2, W2f); return; }
    idx -= 65536;
    if (idx < 65536) { frag256(idx, gw3, W3f); return; }
    idx -= 65536;
    if (idx < 65536) { frag256(idx, gw4, W4f); return; }
    idx -= 65536;
    if (idx < 65536) { int k = idx >> 8, nn = idx & 255; fw1T[idx] = fw1[nn * 256 + k]; return; }
    idx -= 65536;
    if (idx < 65536) { int k = idx >> 8, nn = idx & 255; fw2T[idx] = fw2[nn * 256 + k]; return; }
    idx -= 65536;
    if (idx < 648)   { int k = idx / 24, co = idx - k * 24; wT1[idx] = c1w[co * 27 + k]; return; }
    idx -= 648;
    if (idx < 5184)  { int k = idx / 24, co = idx - k * 24; wT2[idx] = c2w[co * 216 + k]; return; }
    idx -= 5184;
    if (idx < 5184)  { int k = idx / 24, co = idx - k * 24; wT3[idx] = c3w[co * 216 + k]; return; }
    idx -= 5184;
    if (idx < 5184)  { int k = idx / 24, co = idx - k * 24; wT4[idx] = c4w[co * 216 + k]; return; }
}

// ---------------- fused g-MLP: 32x32x16 MFMA, swapped operands (A=W, B=h^T), swizzled LDS ----------------
// r9-best body, untouched (no setprio — r8 regression; no hf-dbuf — r10 null). Pinned at
// ~153us / MfmaUtil 40% across 7 variants; the multi-pipe floor needs wave-specialization
// asm to break — out of polish-session scope.

template <int NKS>
__device__ __forceinline__ void g_quarter(const bf16_t* hs, const bf16_t* __restrict__ wbase0,
                                          const bf16_t* __restrict__ wbase1,
                                          int q, int m31, int half,
                                          bf16x8 (&CUR)[2][4], bf16x8 (&NXT)[2][4],
                                          f32x16 (&acc)[4][2])
{
    if (q + 1 < NKS / 4) {   // prefetch next quarter's wf while this quarter's MFMAs run
#pragma unroll
        for (int k = 0; k < 4; ++k) {
            NXT[0][k] = *(const bf16x8*)(wbase0 + (size_t)((q + 1) * 4 + k) * 512);
            NXT[1][k] = *(const bf16x8*)(wbase1 + (size_t)((q + 1) * 4 + k) * 512);
        }
    }
#pragma unroll
    for (int kk = 0; kk < 4; ++kk) {
        int ks = q * 4 + kk;
        int kc = ks * 2 + half;
        bf16x8 hf[4];
#pragma unroll
        for (int mt = 0; mt < 4; ++mt) {
            int m = mt * 32 + m31;
            hf[mt] = *(const bf16x8*)(hs + m * 256 + ((kc ^ m31) << 3));
        }
#pragma unroll
        for (int mt = 0; mt < 4; ++mt) {
            acc[mt][0] = __builtin_amdgcn_mfma_f32_32x32x16_bf16(CUR[0][kk], hf[mt], acc[mt][0], 0, 0, 0);
            acc[mt][1] = __builtin_amdgcn_mfma_f32_32x32x16_bf16(CUR[1][kk], hf[mt], acc[mt][1], 0, 0, 0);
        }
    }
}

template <int NKS>  // K/16: 4 for layer1, 16 for layers 2-4
__device__ __forceinline__ void g_layer(const bf16_t* hs, const bf16_t* __restrict__ Wf,
                                        int wid, int lane, f32x16 (&acc)[4][2])
{
    int m31 = lane & 31, half = lane >> 5;
#pragma unroll
    for (int mt = 0; mt < 4; ++mt)
#pragma unroll
        for (int nt = 0; nt < 2; ++nt) acc[mt][nt] = (f32x16)(0.f);

    const bf16_t* wbase0 = Wf + (size_t)(((wid * 2 + 0) * NKS) * 64 + lane) * 8;
    const bf16_t* wbase1 = Wf + (size_t)(((wid * 2 + 1) * NKS) * 64 + lane) * 8;
    bf16x8 wA[2][4], wB[2][4];
#pragma unroll
    for (int k = 0; k < 4; ++k) {   // preload quarter 0
        wA[0][k] = *(const bf16x8*)(wbase0 + (size_t)k * 512);
        wA[1][k] = *(const bf16x8*)(wbase1 + (size_t)k * 512);
    }
#pragma unroll
    for (int q = 0; q < NKS / 4; ++q) {
        if ((q & 1) == 0) g_quarter<NKS>(hs, wbase0, wbase1, q, m31, half, wA, wB, acc);
        else              g_quarter<NKS>(hs, wbase0, wbase1, q, m31, half, wB, wA, acc);
    }
}

__device__ __forceinline__ void g_store(bf16_t* hs, const float* __restrict__ bias,
                                        int wid, int lane, f32x16 (&acc)[4][2])
{
    int m31 = lane & 31, half = lane >> 5;
#pragma unroll
    for (int mt = 0; mt < 4; ++mt) {
        int m = mt * 32 + m31;
#pragma unroll
        for (int nt = 0; nt < 2; ++nt) {
            int nbase = (wid * 2 + nt) * 32;
#pragma unroll
            for (int g = 0; g < 4; ++g) {
                int n0 = nbase + g * 8 + half * 4;
                float4 bv = *(const float4*)(bias + n0);
                bf16x4 v;
                v[0] = (bf16_t)fmaxf(acc[mt][nt][g * 4 + 0] + bv.x, 0.f);
                v[1] = (bf16_t)fmaxf(acc[mt][nt][g * 4 + 1] + bv.y, 0.f);
                v[2] = (bf16_t)fmaxf(acc[mt][nt][g * 4 + 2] + bv.z, 0.f);
                v[3] = (bf16_t)fmaxf(acc[mt][nt][g * 4 + 3] + bv.w, 0.f);
                int chunk = n0 >> 3;  // half*4 < 8, so chunk = (nbase + g*8) >> 3
                *(bf16x4*)(hs + m * 256 + ((chunk ^ m31) << 3) + (half << 2)) = v;
            }
        }
    }
}

__global__ void __launch_bounds__(256, 2)
g_mlp(const bf16_t* __restrict__ xf26, const bf16_t* __restrict__ qstb,
      const bf16_t* __restrict__ W1f, const bf16_t* __restrict__ W2f,
      const bf16_t* __restrict__ W3f, const bf16_t* __restrict__ W4f,
      const float* __restrict__ b1, const float* __restrict__ b2,
      const float* __restrict__ b3, const float* __restrict__ b4,
      float* __restrict__ xg5)
{
    __shared__ __align__(16) bf16_t hs[GROWS * 256];   // 65,536 B
    int b    = blockIdx.x / GT_PER_B;
    int tile = blockIdx.x % GT_PER_B;
    int tid  = threadIdx.x;

    // stage features (64 bf16 per row -> chunks 0..7, swizzled)
    for (int i = tid; i < GROWS * 8; i += 256) {
        int m = i >> 3, c = i & 7;
        int p = tile * GROWS + m;
        bf16x8 v;
        if (p < 625) {
            int a = p / 25, cp = p - a * 25;
            const bf16_t* f1 = xf26 + (b * 25 + cp) * 26;
            const bf16_t* f2 = xf26 + (b * 25 + a) * 26;
            const bf16_t* f3 = qstb + b * 11;
#pragma unroll
            for (int j = 0; j < 8; ++j) {
                int col = c * 8 + j;
                bf16_t u = (bf16_t)0.0f;
                if (col < 26) u = f1[col];
                else if (col < 52) u = f2[col - 26];
                else if (col < 63) u = f3[col - 52];
                v[j] = u;
            }
        } else {
#pragma unroll
            for (int j = 0; j < 8; ++j) v[j] = (bf16_t)0.0f;
        }
        *(bf16x8*)(hs + m * 256 + ((c ^ (m & 31)) << 3)) = v;
    }
    __syncthreads();

    int wid = tid >> 6, lane = tid & 63;
    int m31 = lane & 31, half = lane >> 5;
    f32x16 acc[4][2];

    g_layer<4>(hs, W1f, wid, lane, acc);
    __syncthreads(); g_store(hs, b1, wid, lane, acc); __syncthreads();
    g_layer<16>(hs, W2f, wid, lane, acc);
    __syncthreads(); g_store(hs, b2, wid, lane, acc); __syncthreads();
    g_layer<16>(hs, W3f, wid, lane, acc);
    __syncthreads(); g_store(hs, b3, wid, lane, acc); __syncthreads();
    g_layer<16>(hs, W4f, wid, lane, acc);

    // epilogue: relu(acc + b4), mask invalid rows, sum over m, plain store into xg5 slot
#pragma unroll
    for (int nt = 0; nt < 2; ++nt) {
        int nbase = (wid * 2 + nt) * 32;
        float bf[16];
#pragma unroll
        for (int r = 0; r < 16; ++r)
            bf[r] = b4[nbase + (r & 3) + 8 * (r >> 2) + 4 * half];
        f32x16 t = (f32x16)(0.f);
#pragma unroll
        for (int mt = 0; mt < 4; ++mt) {
            int p = tile * GROWS + mt * 32 + m31;
            if (p < 625) {
#pragma unroll
                for (int r = 0; r < 16; ++r)
                    t[r] += fmaxf(acc[mt][nt][r] + bf[r], 0.f);
            }
        }
#pragma unroll
        for (int off = 1; off < 32; off <<= 1) {
#pragma unroll
            for (int r = 0; r < 16; ++r) t[r] += __shfl_xor(t[r], off);
        }
        if (m31 == 0) {
#pragma unroll
            for (int r = 0; r < 16; ++r) {
                int nn = nbase + (r & 3) + 8 * (r >> 2) + 4 * half;
                xg5[(b * GT_PER_B + tile) * 256 + nn] = t[r];
            }
        }
    }
}

// ---------------- f-MLP (fp32) + log_softmax ----------------
// r13 k-split body: 512 threads, thread (t,h) sums k in [h*128,(h+1)*128); LDS combine
// adds halves + bias. 16 waves/CU. Deterministic (fixed split point).
__global__ __launch_bounds__(512) void f_mlp(const float* __restrict__ xg5,
                      const float* __restrict__ fw1T, const float* __restrict__ fb1,
                      const float* __restrict__ fw2T, const float* __restrict__ fb2,
                      const float* __restrict__ fw3, const float* __restrict__ fb3,
                      float* __restrict__ out)
{
    __shared__ float xa[256], xb[256], part[512];
    int b = blockIdx.x;
    int t = threadIdx.x & 255, h = threadIdx.x >> 8;   // h in {0,1}
    if (h == 0) {
        float s0 = 0.f;
#pragma unroll
        for (int i = 0; i < GT_PER_B; ++i) s0 += xg5[(b * GT_PER_B + i) * 256 + t];
        xa[t] = s0;
    }
    __syncthreads();
    // layer 1
    {
        float a = 0.f;
        const float* w = fw1T + (h * 128) * 256 + t;
        for (int k = 0; k < 128; ++k) a += w[k * 256] * xa[h * 128 + k];
        part[h * 256 + t] = a;
    }
    __syncthreads();
    if (h == 0) xb[t] = fmaxf(part[t] + part[256 + t] + fb1[t], 0.f);
    __syncthreads();
    // layer 2
    {
        float a = 0.f;
        const float* w = fw2T + (h * 128) * 256 + t;
        for (int k = 0; k < 128; ++k) a += w[k * 256] * xb[h * 128 + k];
        part[h * 256 + t] = a;
    }
    __syncthreads();
    if (h == 0) xa[t] = fmaxf(part[t] + part[256 + t] + fb2[t], 0.f);
    __syncthreads();
    // layer 3 (10 outputs): 20 threads, (o, hh) halves
    if (threadIdx.x < 20) {
        int o = threadIdx.x % 10, hh = threadIdx.x / 10;
        float s = 0.f;
        for (int k = hh * 128; k < hh * 128 + 128; ++k) s += fw3[o * 256 + k] * xa[k];
        part[hh * 10 + o] = s;
    }
    __syncthreads();
    if (threadIdx.x == 0) {
        float lg[10];
#pragma unroll
        for (int i = 0; i < 10; ++i) lg[i] = part[i] + part[10 + i] + fb3[i];
        float m = lg[0];
        for (int i = 1; i < 10; ++i) m = fmaxf(m, lg[i]);
        float s = 0.f;
        for (int i = 0; i < 10; ++i) s += expf(lg[i] - m);
        float ls = m + logf(s);
        for (int i = 0; i < 10; ++i) out[b * 10 + i] = lg[i] - ls;
    }
}

// ---------------- launch ----------------
extern "C" void kernel_launch(void* const* d_in, const int* in_sizes, int n_in,
                              void* d_out, int out_size, void* d_ws, size_t ws_size,
                              hipStream_t stream)
{
    (void)in_sizes; (void)n_in; (void)out_size; (void)ws_size;
    const float* img  = (const float*)d_in[0];
    const float* qst  = (const float*)d_in[1];
    const float* c1w  = (const float*)d_in[2];
    const float* c1b  = (const float*)d_in[3];
    const float* bn1g = (const float*)d_in[4];
    const float* bn1b = (const float*)d_in[5];
    const float* c2w  = (const float*)d_in[6];
    const float* c2b  = (const float*)d_in[7];
    const float* bn2g = (const float*)d_in[8];
    const float* bn2b = (const float*)d_in[9];
    const float* c3w  = (const float*)d_in[10];
    const float* c3b  = (const float*)d_in[11];
    const float* bn3g = (const float*)d_in[12];
    const float* bn3b = (const float*)d_in[13];
    const float* c4w  = (const float*)d_in[14];
    const float* c4b  = (const float*)d_in[15];
    const float* bn4g = (const float*)d_in[16];
    const float* bn4b = (const float*)d_in[17];
    const float* gw1  = (const float*)d_in[18];
    const float* gb1  = (const float*)d_in[19];
    const float* gw2  = (const float*)d_in[20];
    const float* gb2  = (const float*)d_in[21];
    const float* gw3  = (const float*)d_in[22];
    const float* gb3  = (const float*)d_in[23];
    const float* gw4  = (const float*)d_in[24];
    const float* gb4  = (const float*)d_in[25];
    const float* fw1  = (const float*)d_in[26];
    const float* fb1  = (const float*)d_in[27];
    const float* fw2  = (const float*)d_in[28];
    const float* fb2  = (const float*)d_in[29];
    const float* fw3  = (const float*)d_in[30];
    const float* fb3  = (const float*)d_in[31];

    const int Y1 = 512 * 24 * 38 * 38;
    const int Y2 = 512 * 24 * 19 * 19;
    const int Y3 = 512 * 24 * 10 * 10;
    const int Y4 = 512 * 24 * 5 * 5;

    // stats in DOUBLE at the head of ws (8B-aligned); everything else after
    double* stats = (double*)d_ws;       // [4 layers][24 ch][sum, sumsq] = 192 doubles
    float* fp = (float*)(stats + 192);
    float* y1    = fp;  fp += Y1;
    float* y2    = fp;  fp += Y2;
    float* y3    = fp;  fp += Y3;
    float* y4    = fp;  fp += Y4;
    float* xg5   = fp;  fp += 512 * GT_PER_B * 256;   // per-tile partial sums (no atomics)
    float* fw1T  = fp;  fp += 65536;
    float* fw2T  = fp;  fp += 65536;
    float* wT1   = fp;  fp += 648;       // conv weights transposed [k][24]
    float* wT2   = fp;  fp += 5184;
    float* wT3   = fp;  fp += 5184;
    float* wT4   = fp;  fp += 5184;
    bf16_t* bp   = (bf16_t*)fp;
    bf16_t* xf26 = bp;  bp += 512 * 25 * 26;
    bf16_t* qstb = bp;  bp += 512 * 11;
    bf16_t* W1f  = bp;  bp += 16384;     // g-weights in MFMA frag order
    bf16_t* W2f  = bp;  bp += 65536;
    bf16_t* W3f  = bp;  bp += 65536;
    bf16_t* W4f  = bp;  bp += 65536;

    hipMemsetAsync(stats, 0, 192 * sizeof(double), stream);

    // grid MUST cover all 360,264 work items (ceil -> 1408 blocks)
    prep_weights<<<1408, 256, 0, stream>>>(gw1, gw2, gw3, gw4, fw1, fw2, c1w, c2w, c3w, c4w,
                                           W1f, W2f, W3f, W4f, fw1T, fw2T,
                                           wT1, wT2, wT3, wT4);

    // conv1: 4 row-tiles of 10 per image, 384-thread blocks (6 waves x 4 co)
    conv1_bn<<<2048, 384, 0, stream>>>(img, wT1, c1b, y1, stats + 0);

    // conv2: 2 row-tiles of 10, CIB=12 (2 staging phases; LDS 40.3KB x 4 blocks fits 160KiB)
    conv24_bn<38, 38, 19, 19, 10, 3, 12, 24, 384><<<1024, 384, 0, stream>>>(
        y1, wT2, c2b, stats + 0, bn1g, bn1b, 1.f / (512.f * 1444.f),
        y2, stats + 48, 2);

    // conv3: co-split (12 co per block), 384thr (CPW=2) -> 24 waves/CU
    conv24_bn<19, 19, 10, 10, 10, 2, 12, 12, 384><<<1024, 384, 0, stream>>>(
        y2, wT3, c3b, stats + 48, bn2g, bn2b, 1.f / (512.f * 361.f),
        y3, stats + 96, 1);

    // conv4: co-split (12 co per block), 384thr (CPW=2)
    conv24_bn<10, 10, 5, 5, 5, 1, 12, 12, 384><<<1024, 384, 0, stream>>>(
        y3, wT4, c4b, stats + 96, bn3g, bn3b, 1.f / (512.f * 100.f),
        y4, stats + 144, 1);

    // build_features: one thread per item -> 1272 blocks
    build_features<<<1272, 256, 0, stream>>>(y4, stats + 144, bn4g, bn4b, qst, xf26, qstb);

    g_mlp<<<512 * GT_PER_B, 256, 0, stream>>>(xf26, qstb, W1f, W2f, W3f, W4f,
                                              gb1, gb2, gb3, gb4, xg5);

    // f_mlp: 512 threads (k-split halves) -> 16 waves/CU
    f_mlp<<<512, 512, 0, stream>>>(xg5, fw1T, fb1, fw2T, fb2, fw3, fb3, (float*)d_out);
}